// Round 3
// baseline (2232.747 us; speedup 1.0000x reference)
//
#include <hip/hip_runtime.h>
#include <math.h>

#define HID 128
#define CAP 8192
#define NCHUNK 8
#define SCORE_SCALE 0.2209708691207961f   // 1/(sqrt(32)*0.8)
#define INV_SQRT_HID 0.08838834764831845f // 1/sqrt(128)

typedef unsigned char u8;

__device__ __forceinline__ float4 ld4(const float* p) { return *(const float4*)p; }
__device__ __forceinline__ float nanfix(float v) { return (v != v) ? 0.f : v; }

// ---------------------------------------------------------------------------
// Generic f32 GEMM: C[M,128] = act(Asrc @ W[K,128] + bias) (+resid)
// AMODE: 0 = A ; 1 = A + A2 (fused GINE z=h+agg) ; 2 = concat-gather(tab1[id1],tab2[id2])
// Microtile: rows tr+16i (i<4), cols tc*4+64j (j<2).
//   Per-wave LDS reads: A = 4 distinct b128 (disjoint bank spans, conflict-free),
//   W = 16 addrs at 16B stride -> start banks {0,4,..,28}x2 = 2-way (free, m136).
// NOTE: A2 / resid / C are NOT __restrict__ — C may alias A2 (t1 over agg).
// Safe: all A2 reads are staged before the last barrier; C stores depend on acc
// which depends (through LDS+barrier) on every staged tile.
// ---------------------------------------------------------------------------
template<int AMODE, bool RELU, bool RESID, bool NANFIX>
__global__ __launch_bounds__(256) void gemm128(
    const float* __restrict__ A, const float* A2,
    const int* __restrict__ id1, const int* __restrict__ id2,
    const float* __restrict__ tab1, const float* __restrict__ tab2,
    const float* __restrict__ W, const float* __restrict__ bias,
    const float* resid, float* C,
    int M, int K)
{
    __shared__ float As[64][36];      // stride 36 floats = 9x16B: float4-aligned rows
    __shared__ float Ws[32][HID];
    const int tid = threadIdx.x;
    const int row0 = blockIdx.x * 64;
    const int tr = tid >> 4;          // [0,16): row group
    const int tc = tid & 15;          // [0,16): col group
    float4 acc[4][2];
#pragma unroll
    for (int i = 0; i < 4; ++i)
#pragma unroll
        for (int j = 0; j < 2; ++j) acc[i][j] = make_float4(0.f, 0.f, 0.f, 0.f);

    for (int k0 = 0; k0 < K; k0 += 32) {
        // stage A tile 64x32 (512 float4 slots / 256 thr)
#pragma unroll
        for (int i = 0; i < 2; ++i) {
            int slot = tid + i * 256;
            int r = slot >> 3;
            int kc = (slot & 7) << 2;
            int gr = row0 + r;
            float4 v = make_float4(0.f, 0.f, 0.f, 0.f);
            if (gr < M) {
                int gk = k0 + kc;
                if (AMODE == 2) {
                    if (gk < HID) v = ld4(tab1 + (size_t)id1[gr] * HID + gk);
                    else          v = ld4(tab2 + (size_t)id2[gr] * HID + (gk - HID));
                } else {
                    v = ld4(A + (size_t)gr * K + gk);
                    if (AMODE == 1) {
                        float4 w = ld4(A2 + (size_t)gr * K + gk);
                        v.x += w.x; v.y += w.y; v.z += w.z; v.w += w.w;
                    }
                }
            }
            *(float4*)&As[r][kc] = v;
        }
        // stage W tile 32x128 (1024 float4 slots / 256 thr)
#pragma unroll
        for (int i = 0; i < 4; ++i) {
            int slot = tid + i * 256;
            int kr = slot >> 5;
            int c = (slot & 31) << 2;
            *(float4*)&Ws[kr][c] = ld4(W + (size_t)(k0 + kr) * HID + c);
        }
        __syncthreads();
#pragma unroll
        for (int kk0 = 0; kk0 < 32; kk0 += 4) {
            float4 av[4];
#pragma unroll
            for (int i = 0; i < 4; ++i) av[i] = *(float4*)&As[tr + 16 * i][kk0];
#pragma unroll
            for (int t = 0; t < 4; ++t) {
                int kk = kk0 + t;
                float4 w0 = *(float4*)&Ws[kk][tc * 4];
                float4 w1 = *(float4*)&Ws[kk][tc * 4 + 64];
#pragma unroll
                for (int i = 0; i < 4; ++i) {
                    float a = (t == 0) ? av[i].x : (t == 1) ? av[i].y
                            : (t == 2) ? av[i].z : av[i].w;
                    acc[i][0].x = fmaf(a, w0.x, acc[i][0].x);
                    acc[i][0].y = fmaf(a, w0.y, acc[i][0].y);
                    acc[i][0].z = fmaf(a, w0.z, acc[i][0].z);
                    acc[i][0].w = fmaf(a, w0.w, acc[i][0].w);
                    acc[i][1].x = fmaf(a, w1.x, acc[i][1].x);
                    acc[i][1].y = fmaf(a, w1.y, acc[i][1].y);
                    acc[i][1].z = fmaf(a, w1.z, acc[i][1].z);
                    acc[i][1].w = fmaf(a, w1.w, acc[i][1].w);
                }
            }
        }
        __syncthreads();
    }
#pragma unroll
    for (int j = 0; j < 2; ++j) {
        int c0 = tc * 4 + 64 * j;
        float4 bv = ld4(bias + c0);
#pragma unroll
        for (int i = 0; i < 4; ++i) {
            int gr = row0 + tr + 16 * i;
            if (gr >= M) continue;
            float o[4] = {acc[i][j].x + bv.x, acc[i][j].y + bv.y,
                          acc[i][j].z + bv.z, acc[i][j].w + bv.w};
            if (RELU) {
#pragma unroll
                for (int q = 0; q < 4; ++q) o[q] = o[q] > 0.f ? o[q] : 0.f;
            }
            if (RESID) {
                float4 rv = ld4(resid + (size_t)gr * HID + c0);
                o[0] += rv.x; o[1] += rv.y; o[2] += rv.z; o[3] += rv.w;
            }
            if (NANFIX) {
#pragma unroll
                for (int q = 0; q < 4; ++q) o[q] = nanfix(o[q]);
            }
            *(float4*)(C + (size_t)gr * HID + c0) = make_float4(o[0], o[1], o[2], o[3]);
        }
    }
}

// ---------------------------------------------------------------------------
// CSR build (once per launch; topology is h-independent).
// deg starts at 1 (self-loop), histogram adds real in-edges.
// ---------------------------------------------------------------------------
__global__ void init_deg(int* deg, int N)
{
    int i = blockIdx.x * 256 + threadIdx.x;
    if (i < N) deg[i] = 1;   // self-loop
}

__global__ void hist_kernel(const int* __restrict__ ei, int* deg, int E)
{
    int e = blockIdx.x * 256 + threadIdx.x;
    if (e < E) atomicAdd(&deg[ei[E + e]], 1);
}

// exclusive scan of deg[0..N) -> rowptr[0..N], single block of 1024 threads
__global__ __launch_bounds__(1024) void scan_kernel(
    const int* __restrict__ deg, int* __restrict__ rowptr, int N)
{
    const int T = 1024;
    __shared__ int part[T];
    int t = threadIdx.x;
    int chunk = (N + T - 1) / T;
    int s = t * chunk;
    int e = min(s + chunk, N);
    int sum = 0;
    for (int i = s; i < e; ++i) sum += deg[i];
    part[t] = sum;
    __syncthreads();
    for (int off = 1; off < T; off <<= 1) {
        int v = (t >= off) ? part[t - off] : 0;
        __syncthreads();
        part[t] += v;
        __syncthreads();
    }
    int run = (t == 0) ? 0 : part[t - 1];
    for (int i = s; i < e; ++i) { rowptr[i] = run; run += deg[i]; }
    if (t == 0) rowptr[N] = part[T - 1];
}

__global__ void scatter_kernel(
    const int* __restrict__ ei, const int* __restrict__ eattr,
    const int* __restrict__ rowptr, int* fill,
    int* __restrict__ csrc, int* __restrict__ ceid, int E, int N, int nbm1)
{
    int g = blockIdx.x * 256 + threadIdx.x;
    if (g >= E + N) return;
    int src, dst, eid;
    if (g < E) {
        src = ei[g]; dst = ei[E + g];
        eid = eattr[g]; eid = eid < 0 ? 0 : (eid > nbm1 ? nbm1 : eid);
    } else {
        src = dst = g - E; eid = 0;
    }
    int slot = rowptr[dst] + atomicAdd(&fill[dst], 1);
    csrc[slot] = src;
    ceid[slot] = eid;
}

// ---------------------------------------------------------------------------
// GINE aggregate, CSR gather: agg[dst] = sum_in relu(h[src] + bond[eid]).
// One wave per dst row, float2 per lane (64*2 = 128 dims). No atomics,
// agg fully written (no memset needed).
// ---------------------------------------------------------------------------
__global__ __launch_bounds__(256) void gine_gather(
    const int* __restrict__ rowptr, const int* __restrict__ csrc,
    const int* __restrict__ ceid, const float* __restrict__ h,
    const float* __restrict__ bond, float* __restrict__ agg, int N)
{
    int wid = (blockIdx.x * 256 + threadIdx.x) >> 6;
    int lane = threadIdx.x & 63;
    if (wid >= N) return;
    int beg = rowptr[wid], end = rowptr[wid + 1];
    int d = lane * 2;
    float ax = 0.f, ay = 0.f;
    for (int e = beg; e < end; ++e) {
        int src = csrc[e];
        int eid = ceid[e];
        float2 hv = *(const float2*)(h + (size_t)src * HID + d);
        float2 bv = *(const float2*)(bond + (size_t)eid * HID + d);
        float x0 = hv.x + bv.x, x1 = hv.y + bv.y;
        ax += x0 > 0.f ? x0 : 0.f;
        ay += x1 > 0.f ? x1 : 0.f;
    }
    *(float2*)(agg + (size_t)wid * HID + d) = make_float2(ax, ay);
}

// ---------------------------------------------------------------------------
// Graph LayerNorm stats: sum and sumsq over ALL N*H elements (double accum)
// ---------------------------------------------------------------------------
__global__ __launch_bounds__(256) void ln_stats(
    const float* __restrict__ z, double* __restrict__ stats, int nvec)
{
    double s1 = 0.0, s2 = 0.0;
    for (int i = blockIdx.x * blockDim.x + threadIdx.x; i < nvec;
         i += gridDim.x * blockDim.x) {
        float4 v = ld4(z + (size_t)i * 4);
        s1 += (double)v.x + (double)v.y + (double)v.z + (double)v.w;
        s2 += (double)v.x * v.x + (double)v.y * v.y + (double)v.z * v.z + (double)v.w * v.w;
    }
#pragma unroll
    for (int off = 32; off; off >>= 1) {
        s1 += __shfl_down(s1, off);
        s2 += __shfl_down(s2, off);
    }
    __shared__ double sh[2][4];
    int wid = threadIdx.x >> 6, lane = threadIdx.x & 63;
    if (lane == 0) { sh[0][wid] = s1; sh[1][wid] = s2; }
    __syncthreads();
    if (threadIdx.x == 0) {
        double a = sh[0][0] + sh[0][1] + sh[0][2] + sh[0][3];
        double b = sh[1][0] + sh[1][1] + sh[1][2] + sh[1][3];
        unsafeAtomicAdd(&stats[0], a);
        unsafeAtomicAdd(&stats[1], b);
    }
}

__global__ __launch_bounds__(256) void ln_silu(
    const float* __restrict__ z, const double* __restrict__ stats,
    const float* __restrict__ w, const float* __restrict__ b,
    float* __restrict__ h, int nvec, int total)
{
    double mu = stats[0] / total;
    double var = stats[1] / total - mu * mu;
    float mean = (float)mu;
    float rstd = (float)(1.0 / sqrt(var + 1e-5));
    for (int i = blockIdx.x * blockDim.x + threadIdx.x; i < nvec;
         i += gridDim.x * blockDim.x) {
        float4 v = ld4(z + (size_t)i * 4);
        int c = (i & 31) * 4;
        float o[4] = {v.x, v.y, v.z, v.w};
#pragma unroll
        for (int j = 0; j < 4; ++j) {
            float t = (o[j] - mean) * rstd * w[c + j] + b[c + j];
            t = t / (1.f + __expf(-t));   // silu
            o[j] = nanfix(t);
        }
        *(float4*)(h + (size_t)i * 4) = make_float4(o[0], o[1], o[2], o[3]);
    }
}

// column sums of h (for the broadcast mean query)
__global__ __launch_bounds__(256) void colsum(
    const float* __restrict__ h, float* __restrict__ hsum, int N)
{
    int d = threadIdx.x & 127;
    int half = threadIdx.x >> 7;
    float acc = 0.f;
    for (int r = blockIdx.x * 2 + half; r < N; r += gridDim.x * 2)
        acc += h[(size_t)r * HID + d];
    unsafeAtomicAdd(&hsum[d], acc);
}

// q = (hsum/N) @ wq + bq   (single 128-vector)
__global__ void qproj(const float* __restrict__ hsum, const float* __restrict__ wq,
                      const float* __restrict__ bq, float* __restrict__ q, float invN)
{
    __shared__ float q0[HID];
    int c = threadIdx.x;
    q0[c] = hsum[c] * invN;
    __syncthreads();
    float acc = bq[c];
    for (int k = 0; k < HID; ++k) acc += q0[k] * wq[k * HID + c];
    q[c] = acc;
}

// t[n,head] = dot(q_head, K[n,head]) * SCORE_SCALE
__global__ __launch_bounds__(256) void score_kernel(
    const float* __restrict__ Kb, const float* __restrict__ q,
    float* __restrict__ t, int N)
{
    int gid = blockIdx.x * 256 + threadIdx.x;
    int n = gid >> 6, lane = gid & 63;
    if (n >= N) return;
    float2 kv = *(const float2*)(Kb + (size_t)n * HID + lane * 2);
    float2 qv = *(const float2*)(q + lane * 2);
    float p = kv.x * qv.x + kv.y * qv.y;
    p += __shfl_xor(p, 1);
    p += __shfl_xor(p, 2);
    p += __shfl_xor(p, 4);
    p += __shfl_xor(p, 8);
    if ((lane & 15) == 0) t[n * 4 + (lane >> 4)] = p * SCORE_SCALE;
}

// mask layout: bit1 = float32 (word 0x3F800000 seen), bit0 = packed bytes
// (word>1 but not float-1.0). Neither -> int32 0/1 words.
__global__ void detect_mask(const void* mask, int nwords, int* flag)
{
    const unsigned* m = (const unsigned*)mask;
    int f = 0;
    for (int i = threadIdx.x; i < nwords; i += blockDim.x) {
        unsigned w = m[i];
        if (w == 0x3F800000u) f |= 2;
        else if (w > 1u) f |= 1;
    }
    if (f) atomicOr(flag, f);
}

__device__ __forceinline__ bool maskbit(const void* mask, int layout, size_t idx)
{
    if (layout & 2) return ((const float*)mask)[idx] != 0.f;
    if (layout & 1) return ((const u8*)mask)[idx] != 0;
    return ((const int*)mask)[idx] != 0;
}

// per-subgraph masked-node index lists
__global__ __launch_bounds__(256) void compact(
    const void* __restrict__ mask, const int* __restrict__ flag,
    int* __restrict__ cnt, int* __restrict__ list, int N)
{
    int s = blockIdx.y;
    int n = blockIdx.x * 256 + threadIdx.x;
    if (n >= N) return;
    if (maskbit(mask, *flag, (size_t)s * N + n)) {
        int p = atomicAdd(&cnt[s], 1);
        if (p < CAP) list[(size_t)s * CAP + p] = n;
    }
}

// per-(subgraph,head) online softmax max m and denom l
__global__ __launch_bounds__(256) void att_ml(
    const float* __restrict__ t, const int* __restrict__ cnt,
    const int* __restrict__ list, const void* __restrict__ mask,
    const int* __restrict__ flag, float* __restrict__ ml, int N)
{
    int s = blockIdx.x;
    int tid = threadIdx.x;
    int c = cnt[s];
    float m4[4] = {-INFINITY, -INFINITY, -INFINITY, -INFINITY};
    float l4[4] = {0.f, 0.f, 0.f, 0.f};
    auto upd = [&](float4 tv) {
        float vv[4] = {tv.x, tv.y, tv.z, tv.w};
#pragma unroll
        for (int h2 = 0; h2 < 4; ++h2) {
            float v = vv[h2];
            if (v > m4[h2]) {
                l4[h2] = l4[h2] * __expf(m4[h2] - v);
                m4[h2] = v;
                l4[h2] += 1.f;
            } else {
                l4[h2] += __expf(v - m4[h2]);
            }
        }
    };
    if (c <= CAP) {
        const int* ls = list + (size_t)s * CAP;
        for (int j = tid; j < c; j += 256) upd(ld4(t + ls[j] * 4));
    } else {  // defensive fallback (statistically unreachable)
        int fb = *flag;
        for (int n = tid; n < N; n += 256)
            if (maskbit(mask, fb, (size_t)s * N + n)) upd(ld4(t + n * 4));
    }
    __shared__ float sm[4][256];
    __shared__ float sl[4][256];
#pragma unroll
    for (int h2 = 0; h2 < 4; ++h2) { sm[h2][tid] = m4[h2]; sl[h2][tid] = l4[h2]; }
    __syncthreads();
    for (int st = 128; st >= 1; st >>= 1) {
        if (tid < st) {
#pragma unroll
            for (int h2 = 0; h2 < 4; ++h2) {
                float m1 = sm[h2][tid], m2 = sm[h2][tid + st];
                float l1 = sl[h2][tid], l2 = sl[h2][tid + st];
                float M = fmaxf(m1, m2);
                float e1 = (m1 == M) ? l1 : l1 * __expf(m1 - M);
                float e2 = (m2 == M) ? l2 : l2 * __expf(m2 - M);
                sm[h2][tid] = M; sl[h2][tid] = e1 + e2;
            }
        }
        __syncthreads();
    }
    if (tid < 4) { ml[s * 8 + tid] = sm[tid][0]; ml[s * 8 + 4 + tid] = sl[tid][0]; }
}

// weighted V accumulation: sub[s,:] += sum_n softmax * V[n,:]  (chunked for TLP)
__global__ __launch_bounds__(256) void att_pv(
    const float* __restrict__ t, const float* __restrict__ V,
    const int* __restrict__ cnt, const int* __restrict__ list,
    const void* __restrict__ mask, const int* __restrict__ flag,
    const float* __restrict__ ml, float* __restrict__ sub, int N)
{
    int s = blockIdx.y, chunk = blockIdx.x;
    int tid = threadIdx.x;
    int d = tid & 127, half = tid >> 7, hh = d >> 5;
    float m = ml[s * 8 + hh];
    float l = ml[s * 8 + 4 + hh];
    float rl = (l > 0.f) ? 1.f / l : 0.f;
    int c = cnt[s];
    bool uselist = (c <= CAP);
    int L = uselist ? c : N;
    int per = (L + NCHUNK - 1) / NCHUNK;
    int start = chunk * per;
    int end = min(start + per, L);
    int fb = uselist ? 0 : *flag;
    float acc = 0.f;
    for (int j = start + half; j < end; j += 2) {
        int n;
        if (uselist) {
            n = list[(size_t)s * CAP + j];
        } else {
            n = j;
            if (!maskbit(mask, fb, (size_t)s * N + n)) continue;
        }
        float w = __expf(t[n * 4 + hh] - m);
        acc += w * V[(size_t)n * HID + d];
    }
    acc *= rl;
    unsafeAtomicAdd(&sub[(size_t)s * HID + d], acc);
}

// subo = nan_to_num(sub @ wo + bo)
__global__ void wo_kernel(const float* __restrict__ sub, const float* __restrict__ wo,
                          const float* __restrict__ bo, float* __restrict__ subo)
{
    int s = blockIdx.x, c = threadIdx.x;
    __shared__ float row[HID];
    row[c] = sub[(size_t)s * HID + c];
    __syncthreads();
    float acc = bo[c];
    for (int k = 0; k < HID; ++k) acc += row[k] * wo[k * HID + c];
    subo[(size_t)s * HID + c] = nanfix(acc);
}

__global__ void sg_kernel(const float* __restrict__ subo, const float* __restrict__ q,
                          float* __restrict__ sg, int S)
{
    int s = blockIdx.x * blockDim.x + threadIdx.x;
    if (s >= S) return;
    float acc = 0.f;
    for (int k = 0; k < HID; ++k) acc += subo[(size_t)s * HID + k] * q[k];
    sg[s] = nanfix(acc * INV_SQRT_HID);
}

// top-4 (first-index tie break, desc), softmax weights, weighted sum of subo rows
__global__ void topk_kernel(const float* __restrict__ sg, const float* __restrict__ subo,
                            float* __restrict__ out)
{
    __shared__ float sv[256];
    __shared__ float rv[128];
    __shared__ int ri[128];
    __shared__ int topi[4];
    __shared__ float topv[4];
    __shared__ float tw[4];
    int tid = threadIdx.x;  // 128 threads
    sv[tid] = sg[tid];
    sv[tid + 128] = sg[tid + 128];
    __syncthreads();
    for (int it = 0; it < 4; ++it) {
        float v1 = sv[tid], v2 = sv[tid + 128];
        float bvv; int bi;
        if (v2 > v1) { bvv = v2; bi = tid + 128; } else { bvv = v1; bi = tid; }
        rv[tid] = bvv; ri[tid] = bi;
        __syncthreads();
        for (int st = 64; st >= 1; st >>= 1) {
            if (tid < st) {
                float ov = rv[tid + st]; int oi = ri[tid + st];
                if (ov > rv[tid] || (ov == rv[tid] && oi < ri[tid])) {
                    rv[tid] = ov; ri[tid] = oi;
                }
            }
            __syncthreads();
        }
        if (tid == 0) {
            topv[it] = rv[0]; topi[it] = ri[0];
            sv[ri[0]] = -INFINITY;
        }
        __syncthreads();
    }
    if (tid == 0) {
        float mx = topv[0], ssum = 0.f, e[4];
#pragma unroll
        for (int i = 0; i < 4; ++i) { e[i] = __expf(topv[i] - mx); ssum += e[i]; }
#pragma unroll
        for (int i = 0; i < 4; ++i) tw[i] = e[i] / ssum;
    }
    __syncthreads();
    float acc = 0.f;
#pragma unroll
    for (int i = 0; i < 4; ++i) acc += tw[i] * subo[(size_t)topi[i] * HID + tid];
    out[tid] = acc;
}

// ---------------------------------------------------------------------------
extern "C" void kernel_launch(void* const* d_in, const int* in_sizes, int n_in,
                              void* d_out, int out_size, void* d_ws, size_t ws_size,
                              hipStream_t stream)
{
    const int* atom_ids   = (const int*)d_in[0];
    const int* fp_ids     = (const int*)d_in[1];
    const int* ei         = (const int*)d_in[2];
    const int* eattr      = (const int*)d_in[3];
    const void* mask      = d_in[4];
    const float* emb_atom = (const float*)d_in[5];
    const float* emb_fp   = (const float*)d_in[6];
    const float* emb_bond = (const float*)d_in[7];
    const float* w_proj   = (const float*)d_in[8];
    const float* b_proj   = (const float*)d_in[9];
    const float* mlp_w1   = (const float*)d_in[10];
    const float* mlp_b1   = (const float*)d_in[11];
    const float* mlp_w2   = (const float*)d_in[12];
    const float* mlp_b2   = (const float*)d_in[13];
    const float* ln_w     = (const float*)d_in[14];
    const float* ln_b     = (const float*)d_in[15];
    const float* wq       = (const float*)d_in[16];
    const float* bq       = (const float*)d_in[17];
    const float* wk       = (const float*)d_in[18];
    const float* bk       = (const float*)d_in[19];
    const float* wvp      = (const float*)d_in[20];
    const float* bvp      = (const float*)d_in[21];
    const float* wo       = (const float*)d_in[22];
    const float* bo       = (const float*)d_in[23];
    const float* sgq      = (const float*)d_in[24];

    const int N = in_sizes[0];
    const int E = in_sizes[3];
    const int S = in_sizes[4] / N;           // 256
    const int NBM1 = in_sizes[7] / HID - 1;  // bond-id clamp limit

    char* p = (char*)d_ws;
    auto alloc = [&](size_t b) -> char* {
        char* r = p; p += (b + 255) & ~(size_t)255; return r;
    };
    float* hbuf   = (float*)alloc((size_t)N * HID * 4);
    float* abuf   = (float*)alloc((size_t)N * HID * 4);  // agg -> t1 -> K
    float* zbuf   = (float*)alloc((size_t)N * HID * 4);  // z -> V
    float* tsc    = (float*)alloc((size_t)N * 4 * 4);
    int* deg      = (int*)alloc((size_t)N * 4);
    int* rowptr   = (int*)alloc((size_t)(N + 1) * 4);
    int* fill     = (int*)alloc((size_t)N * 4);
    int* csrc     = (int*)alloc((size_t)(E + N) * 4);
    int* ceid     = (int*)alloc((size_t)(E + N) * 4);
    float* hsum   = (float*)alloc(512);
    double* stats = (double*)alloc(256);
    float* qvec   = (float*)alloc(512);
    float* mlbuf  = (float*)alloc((size_t)S * 8 * 4);
    int* cnt      = (int*)alloc((size_t)S * 4);
    int* flag     = (int*)alloc(256);
    int* list     = (int*)alloc((size_t)S * CAP * 4);
    float* sub    = (float*)alloc((size_t)S * HID * 4);
    float* subo   = (float*)alloc((size_t)S * HID * 4);
    float* sgsc   = (float*)alloc((size_t)S * 4);

    const int mblocks = (N + 63) / 64;

    // mask layout detection (independent of everything else)
    hipMemsetAsync(flag, 0, 4, stream);
    detect_mask<<<1, 256, 0, stream>>>(mask, 2048, flag);

    // CSR build (once; topology is h-independent)
    init_deg<<<(N + 255) / 256, 256, 0, stream>>>(deg, N);
    hist_kernel<<<(E + 255) / 256, 256, 0, stream>>>(ei, deg, E);
    scan_kernel<<<1, 1024, 0, stream>>>(deg, rowptr, N);
    hipMemsetAsync(fill, 0, (size_t)N * 4, stream);
    scatter_kernel<<<(E + N + 255) / 256, 256, 0, stream>>>(
        ei, eattr, rowptr, fill, csrc, ceid, E, N, NBM1);

    // node features: x = nan_to_num(concat(emb_atom[a], emb_fp[f]) @ w_proj + b)
    gemm128<2, false, false, true><<<mblocks, 256, 0, stream>>>(
        nullptr, nullptr, atom_ids, fp_ids, emb_atom, emb_fp,
        w_proj, b_proj, nullptr, hbuf, N, 2 * HID);

    for (int l = 0; l < 3; ++l) {
        gine_gather<<<(N * 64 + 255) / 256, 256, 0, stream>>>(
            rowptr, csrc, ceid, hbuf, emb_bond, abuf, N);
        // t1 = relu((h+agg) @ w1 + b1)   (t1 overwrites agg; row-private, safe)
        gemm128<1, true, false, false><<<mblocks, 256, 0, stream>>>(
            hbuf, abuf, nullptr, nullptr, nullptr, nullptr,
            mlp_w1 + (size_t)l * HID * HID, mlp_b1 + (size_t)l * HID,
            nullptr, abuf, N, HID);
        // z = t1 @ w2 + b2 + h
        gemm128<0, false, true, false><<<mblocks, 256, 0, stream>>>(
            abuf, nullptr, nullptr, nullptr, nullptr, nullptr,
            mlp_w2 + (size_t)l * HID * HID, mlp_b2 + (size_t)l * HID,
            hbuf, zbuf, N, HID);
        hipMemsetAsync(stats, 0, 16, stream);
        ln_stats<<<1024, 256, 0, stream>>>(zbuf, stats, N * HID / 4);
        ln_silu<<<1024, 256, 0, stream>>>(zbuf, stats, ln_w + (size_t)l * HID,
                                          ln_b + (size_t)l * HID, hbuf,
                                          N * HID / 4, N * HID);
    }

    // attention pool
    hipMemsetAsync(hsum, 0, 512, stream);
    colsum<<<256, 256, 0, stream>>>(hbuf, hsum, N);
    qproj<<<1, 128, 0, stream>>>(hsum, wq, bq, qvec, 1.0f / (float)N);
    float* Kbuf = abuf;   // t1 dead
    float* Vbuf = zbuf;   // z dead
    gemm128<0, false, false, false><<<mblocks, 256, 0, stream>>>(
        hbuf, nullptr, nullptr, nullptr, nullptr, nullptr, wk, bk, nullptr, Kbuf, N, HID);
    gemm128<0, false, false, false><<<mblocks, 256, 0, stream>>>(
        hbuf, nullptr, nullptr, nullptr, nullptr, nullptr, wvp, bvp, nullptr, Vbuf, N, HID);
    score_kernel<<<(N * 64 + 255) / 256, 256, 0, stream>>>(Kbuf, qvec, tsc, N);

    hipMemsetAsync(cnt, 0, (size_t)S * 4, stream);
    compact<<<dim3((N + 255) / 256, S), 256, 0, stream>>>(mask, flag, cnt, list, N);
    att_ml<<<S, 256, 0, stream>>>(tsc, cnt, list, mask, flag, mlbuf, N);
    hipMemsetAsync(sub, 0, (size_t)S * HID * 4, stream);
    att_pv<<<dim3(NCHUNK, S), 256, 0, stream>>>(tsc, Vbuf, cnt, list, mask, flag,
                                                mlbuf, sub, N);
    wo_kernel<<<S, 128, 0, stream>>>(sub, wo, bo, subo);
    sg_kernel<<<1, 256, 0, stream>>>(subo, sgq, sgsc, S);
    topk_kernel<<<1, 128, 0, stream>>>(sgsc, subo, (float*)d_out);
}

// Round 6
// 1229.491 us; speedup vs baseline: 1.8160x; 1.8160x over previous
//
#include <hip/hip_runtime.h>
#include <math.h>

#define HID 128
#define CAP 8192
#define NCHUNK 8
#define CNTSTRIDE 32                      // one cnt per 128B cacheline (atomic-contention fix)
#define SCORE_SCALE 0.2209708691207961f   // 1/(sqrt(32)*0.8)
#define INV_SQRT_HID 0.08838834764831845f // 1/sqrt(128)

typedef unsigned char u8;

__device__ __forceinline__ float4 ld4(const float* p) { return *(const float4*)p; }
__device__ __forceinline__ float nanfix(float v) { return (v != v) ? 0.f : v; }

// ---------------------------------------------------------------------------
// Generic f32 GEMM: C[M,128] = act(Asrc @ W[K,128] + bias) (+resid)
// AMODE: 0 = A ; 1 = A + A2 (fused GINE z=h+agg) ; 2 = concat-gather(tab1[id1],tab2[id2])
// Microtile: rows tr+16i (i<4), cols tc*4+64j (j<2).
// NOTE: A2 / resid / C are NOT __restrict__ — C may alias A2 (t1 over agg).
// ---------------------------------------------------------------------------
template<int AMODE, bool RELU, bool RESID, bool NANFIX>
__global__ __launch_bounds__(256) void gemm128(
    const float* __restrict__ A, const float* A2,
    const int* __restrict__ id1, const int* __restrict__ id2,
    const float* __restrict__ tab1, const float* __restrict__ tab2,
    const float* __restrict__ W, const float* __restrict__ bias,
    const float* resid, float* C,
    int M, int K)
{
    __shared__ float As[64][36];      // stride 36 floats = 9x16B: float4-aligned rows
    __shared__ float Ws[32][HID];
    const int tid = threadIdx.x;
    const int row0 = blockIdx.x * 64;
    const int tr = tid >> 4;          // [0,16): row group
    const int tc = tid & 15;          // [0,16): col group
    float4 acc[4][2];
#pragma unroll
    for (int i = 0; i < 4; ++i)
#pragma unroll
        for (int j = 0; j < 2; ++j) acc[i][j] = make_float4(0.f, 0.f, 0.f, 0.f);

    for (int k0 = 0; k0 < K; k0 += 32) {
        // stage A tile 64x32 (512 float4 slots / 256 thr)
#pragma unroll
        for (int i = 0; i < 2; ++i) {
            int slot = tid + i * 256;
            int r = slot >> 3;
            int kc = (slot & 7) << 2;
            int gr = row0 + r;
            float4 v = make_float4(0.f, 0.f, 0.f, 0.f);
            if (gr < M) {
                int gk = k0 + kc;
                if (AMODE == 2) {
                    if (gk < HID) v = ld4(tab1 + (size_t)id1[gr] * HID + gk);
                    else          v = ld4(tab2 + (size_t)id2[gr] * HID + (gk - HID));
                } else {
                    v = ld4(A + (size_t)gr * K + gk);
                    if (AMODE == 1) {
                        float4 w = ld4(A2 + (size_t)gr * K + gk);
                        v.x += w.x; v.y += w.y; v.z += w.z; v.w += w.w;
                    }
                }
            }
            *(float4*)&As[r][kc] = v;
        }
        // stage W tile 32x128 (1024 float4 slots / 256 thr)
#pragma unroll
        for (int i = 0; i < 4; ++i) {
            int slot = tid + i * 256;
            int kr = slot >> 5;
            int c = (slot & 31) << 2;
            *(float4*)&Ws[kr][c] = ld4(W + (size_t)(k0 + kr) * HID + c);
        }
        __syncthreads();
#pragma unroll
        for (int kk0 = 0; kk0 < 32; kk0 += 4) {
            float4 av[4];
#pragma unroll
            for (int i = 0; i < 4; ++i) av[i] = *(float4*)&As[tr + 16 * i][kk0];
#pragma unroll
            for (int t = 0; t < 4; ++t) {
                int kk = kk0 + t;
                float4 w0 = *(float4*)&Ws[kk][tc * 4];
                float4 w1 = *(float4*)&Ws[kk][tc * 4 + 64];
#pragma unroll
                for (int i = 0; i < 4; ++i) {
                    float a = (t == 0) ? av[i].x : (t == 1) ? av[i].y
                            : (t == 2) ? av[i].z : av[i].w;
                    acc[i][0].x = fmaf(a, w0.x, acc[i][0].x);
                    acc[i][0].y = fmaf(a, w0.y, acc[i][0].y);
                    acc[i][0].z = fmaf(a, w0.z, acc[i][0].z);
                    acc[i][0].w = fmaf(a, w0.w, acc[i][0].w);
                    acc[i][1].x = fmaf(a, w1.x, acc[i][1].x);
                    acc[i][1].y = fmaf(a, w1.y, acc[i][1].y);
                    acc[i][1].z = fmaf(a, w1.z, acc[i][1].z);
                    acc[i][1].w = fmaf(a, w1.w, acc[i][1].w);
                }
            }
        }
        __syncthreads();
    }
#pragma unroll
    for (int j = 0; j < 2; ++j) {
        int c0 = tc * 4 + 64 * j;
        float4 bv = ld4(bias + c0);
#pragma unroll
        for (int i = 0; i < 4; ++i) {
            int gr = row0 + tr + 16 * i;
            if (gr >= M) continue;
            float o[4] = {acc[i][j].x + bv.x, acc[i][j].y + bv.y,
                          acc[i][j].z + bv.z, acc[i][j].w + bv.w};
            if (RELU) {
#pragma unroll
                for (int q = 0; q < 4; ++q) o[q] = o[q] > 0.f ? o[q] : 0.f;
            }
            if (RESID) {
                float4 rv = ld4(resid + (size_t)gr * HID + c0);
                o[0] += rv.x; o[1] += rv.y; o[2] += rv.z; o[3] += rv.w;
            }
            if (NANFIX) {
#pragma unroll
                for (int q = 0; q < 4; ++q) o[q] = nanfix(o[q]);
            }
            *(float4*)(C + (size_t)gr * HID + c0) = make_float4(o[0], o[1], o[2], o[3]);
        }
    }
}

// ---------------------------------------------------------------------------
// CSR build (once per launch; topology is h-independent).
// ---------------------------------------------------------------------------
__global__ void init_deg(int* deg, int N)
{
    int i = blockIdx.x * 256 + threadIdx.x;
    if (i < N) deg[i] = 1;   // self-loop
}

__global__ void hist_kernel(const int* __restrict__ ei, int* deg, int E)
{
    int e = blockIdx.x * 256 + threadIdx.x;
    if (e < E) atomicAdd(&deg[ei[E + e]], 1);
}

// exclusive scan of deg[0..N) -> rowptr[0..N], single block of 1024 threads
__global__ __launch_bounds__(1024) void scan_kernel(
    const int* __restrict__ deg, int* __restrict__ rowptr, int N)
{
    const int T = 1024;
    __shared__ int part[T];
    int t = threadIdx.x;
    int chunk = (N + T - 1) / T;
    int s = t * chunk;
    int e = min(s + chunk, N);
    int sum = 0;
    for (int i = s; i < e; ++i) sum += deg[i];
    part[t] = sum;
    __syncthreads();
    for (int off = 1; off < T; off <<= 1) {
        int v = (t >= off) ? part[t - off] : 0;
        __syncthreads();
        part[t] += v;
        __syncthreads();
    }
    int run = (t == 0) ? 0 : part[t - 1];
    for (int i = s; i < e; ++i) { rowptr[i] = run; run += deg[i]; }
    if (t == 0) rowptr[N] = part[T - 1];
}

__global__ void scatter_kernel(
    const int* __restrict__ ei, const int* __restrict__ eattr,
    const int* __restrict__ rowptr, int* fill,
    int* __restrict__ csrc, int* __restrict__ ceid, int E, int N, int nbm1)
{
    int g = blockIdx.x * 256 + threadIdx.x;
    if (g >= E + N) return;
    int src, dst, eid;
    if (g < E) {
        src = ei[g]; dst = ei[E + g];
        eid = eattr[g]; eid = eid < 0 ? 0 : (eid > nbm1 ? nbm1 : eid);
    } else {
        src = dst = g - E; eid = 0;
    }
    int slot = rowptr[dst] + atomicAdd(&fill[dst], 1);
    csrc[slot] = src;
    ceid[slot] = eid;
}

// ---------------------------------------------------------------------------
// GINE aggregate, CSR gather: agg[dst] = sum_in relu(h[src] + bond[eid]).
// One wave per dst row, float2 per lane. No atomics; agg fully written.
// ---------------------------------------------------------------------------
__global__ __launch_bounds__(256) void gine_gather(
    const int* __restrict__ rowptr, const int* __restrict__ csrc,
    const int* __restrict__ ceid, const float* __restrict__ h,
    const float* __restrict__ bond, float* __restrict__ agg, int N)
{
    int wid = (blockIdx.x * 256 + threadIdx.x) >> 6;
    int lane = threadIdx.x & 63;
    if (wid >= N) return;
    int beg = rowptr[wid], end = rowptr[wid + 1];
    int d = lane * 2;
    float ax = 0.f, ay = 0.f;
    for (int e = beg; e < end; ++e) {
        int src = csrc[e];
        int eid = ceid[e];
        float2 hv = *(const float2*)(h + (size_t)src * HID + d);
        float2 bv = *(const float2*)(bond + (size_t)eid * HID + d);
        float x0 = hv.x + bv.x, x1 = hv.y + bv.y;
        ax += x0 > 0.f ? x0 : 0.f;
        ay += x1 > 0.f ? x1 : 0.f;
    }
    *(float2*)(agg + (size_t)wid * HID + d) = make_float2(ax, ay);
}

// ---------------------------------------------------------------------------
// Graph LayerNorm stats: sum and sumsq over ALL N*H elements (double accum)
// ---------------------------------------------------------------------------
__global__ __launch_bounds__(256) void ln_stats(
    const float* __restrict__ z, double* __restrict__ stats, int nvec)
{
    double s1 = 0.0, s2 = 0.0;
    for (int i = blockIdx.x * blockDim.x + threadIdx.x; i < nvec;
         i += gridDim.x * blockDim.x) {
        float4 v = ld4(z + (size_t)i * 4);
        s1 += (double)v.x + (double)v.y + (double)v.z + (double)v.w;
        s2 += (double)v.x * v.x + (double)v.y * v.y + (double)v.z * v.z + (double)v.w * v.w;
    }
#pragma unroll
    for (int off = 32; off; off >>= 1) {
        s1 += __shfl_down(s1, off);
        s2 += __shfl_down(s2, off);
    }
    __shared__ double sh[2][4];
    int wid = threadIdx.x >> 6, lane = threadIdx.x & 63;
    if (lane == 0) { sh[0][wid] = s1; sh[1][wid] = s2; }
    __syncthreads();
    if (threadIdx.x == 0) {
        double a = sh[0][0] + sh[0][1] + sh[0][2] + sh[0][3];
        double b = sh[1][0] + sh[1][1] + sh[1][2] + sh[1][3];
        unsafeAtomicAdd(&stats[0], a);
        unsafeAtomicAdd(&stats[1], b);
    }
}

__global__ __launch_bounds__(256) void ln_silu(
    const float* __restrict__ z, const double* __restrict__ stats,
    const float* __restrict__ w, const float* __restrict__ b,
    float* __restrict__ h, int nvec, int total)
{
    double mu = stats[0] / total;
    double var = stats[1] / total - mu * mu;
    float mean = (float)mu;
    float rstd = (float)(1.0 / sqrt(var + 1e-5));
    for (int i = blockIdx.x * blockDim.x + threadIdx.x; i < nvec;
         i += gridDim.x * blockDim.x) {
        float4 v = ld4(z + (size_t)i * 4);
        int c = (i & 31) * 4;
        float o[4] = {v.x, v.y, v.z, v.w};
#pragma unroll
        for (int j = 0; j < 4; ++j) {
            float t = (o[j] - mean) * rstd * w[c + j] + b[c + j];
            t = t / (1.f + __expf(-t));   // silu
            o[j] = nanfix(t);
        }
        *(float4*)(h + (size_t)i * 4) = make_float4(o[0], o[1], o[2], o[3]);
    }
}

// column sums of h (for the broadcast mean query)
__global__ __launch_bounds__(256) void colsum(
    const float* __restrict__ h, float* __restrict__ hsum, int N)
{
    int d = threadIdx.x & 127;
    int half = threadIdx.x >> 7;
    float acc = 0.f;
    for (int r = blockIdx.x * 2 + half; r < N; r += gridDim.x * 2)
        acc += h[(size_t)r * HID + d];
    unsafeAtomicAdd(&hsum[d], acc);
}

// q = (hsum/N) @ wq + bq   (single 128-vector)
__global__ void qproj(const float* __restrict__ hsum, const float* __restrict__ wq,
                      const float* __restrict__ bq, float* __restrict__ q, float invN)
{
    __shared__ float q0[HID];
    int c = threadIdx.x;
    q0[c] = hsum[c] * invN;
    __syncthreads();
    float acc = bq[c];
    for (int k = 0; k < HID; ++k) acc += q0[k] * wq[k * HID + c];
    q[c] = acc;
}

// t[n,head] = dot(q_head, K[n,head]) * SCORE_SCALE
__global__ __launch_bounds__(256) void score_kernel(
    const float* __restrict__ Kb, const float* __restrict__ q,
    float* __restrict__ t, int N)
{
    int gid = blockIdx.x * 256 + threadIdx.x;
    int n = gid >> 6, lane = gid & 63;
    if (n >= N) return;
    float2 kv = *(const float2*)(Kb + (size_t)n * HID + lane * 2);
    float2 qv = *(const float2*)(q + lane * 2);
    float p = kv.x * qv.x + kv.y * qv.y;
    p += __shfl_xor(p, 1);
    p += __shfl_xor(p, 2);
    p += __shfl_xor(p, 4);
    p += __shfl_xor(p, 8);
    if ((lane & 15) == 0) t[n * 4 + (lane >> 4)] = p * SCORE_SCALE;
}

// mask layout: bit1 = float32 (word 0x3F800000 seen), bit0 = packed bytes
__global__ void detect_mask(const void* mask, int nwords, int* flag)
{
    const unsigned* m = (const unsigned*)mask;
    int f = 0;
    for (int i = threadIdx.x; i < nwords; i += blockDim.x) {
        unsigned w = m[i];
        if (w == 0x3F800000u) f |= 2;
        else if (w > 1u) f |= 1;
    }
    if (f) atomicOr(flag, f);
}

__device__ __forceinline__ bool maskbit(const void* mask, int layout, size_t idx)
{
    if (layout & 2) return ((const float*)mask)[idx] != 0.f;
    if (layout & 1) return ((const u8*)mask)[idx] != 0;
    return ((const int*)mask)[idx] != 0;
}

// ---------------------------------------------------------------------------
// per-subgraph masked-node index lists — ballot-aggregated:
// one atomic per BLOCK (was: per set bit), cnt padded to 128B stride.
// In-block order preserved (wave prefix), block order arbitrary (sum-order only).
// ---------------------------------------------------------------------------
__global__ __launch_bounds__(256) void compact(
    const void* __restrict__ mask, const int* __restrict__ flag,
    int* __restrict__ cnt, int* __restrict__ list, int N)
{
    int s = blockIdx.y;
    int n = blockIdx.x * 256 + threadIdx.x;
    int layout = *flag;
    bool pred = (n < N) && maskbit(mask, layout, (size_t)s * N + n);
    unsigned long long ball = __ballot(pred);
    int lane = threadIdx.x & 63;
    int wid = threadIdx.x >> 6;
    int before = __popcll(ball & ((1ull << lane) - 1ull));
    __shared__ int wcnt[4];
    __shared__ int wbase[4];
    if (lane == 0) wcnt[wid] = __popcll(ball);
    __syncthreads();
    if (threadIdx.x == 0) {
        int c0 = wcnt[0], c1 = wcnt[1], c2 = wcnt[2], c3 = wcnt[3];
        int total = c0 + c1 + c2 + c3;
        int base = total ? atomicAdd(&cnt[s * CNTSTRIDE], total) : 0;
        wbase[0] = base;
        wbase[1] = base + c0;
        wbase[2] = base + c0 + c1;
        wbase[3] = base + c0 + c1 + c2;
    }
    __syncthreads();
    if (pred) {
        int p = wbase[wid] + before;
        if (p < CAP) list[(size_t)s * CAP + p] = n;
    }
}

// per-(subgraph,head) online softmax max m and denom l
__global__ __launch_bounds__(256) void att_ml(
    const float* __restrict__ t, const int* __restrict__ cnt,
    const int* __restrict__ list, const void* __restrict__ mask,
    const int* __restrict__ flag, float* __restrict__ ml, int N)
{
    int s = blockIdx.x;
    int tid = threadIdx.x;
    int c = cnt[s * CNTSTRIDE];
    float m4[4] = {-INFINITY, -INFINITY, -INFINITY, -INFINITY};
    float l4[4] = {0.f, 0.f, 0.f, 0.f};
    auto upd = [&](float4 tv) {
        float vv[4] = {tv.x, tv.y, tv.z, tv.w};
#pragma unroll
        for (int h2 = 0; h2 < 4; ++h2) {
            float v = vv[h2];
            if (v > m4[h2]) {
                l4[h2] = l4[h2] * __expf(m4[h2] - v);
                m4[h2] = v;
                l4[h2] += 1.f;
            } else {
                l4[h2] += __expf(v - m4[h2]);
            }
        }
    };
    if (c <= CAP) {
        const int* ls = list + (size_t)s * CAP;
        for (int j = tid; j < c; j += 256) upd(ld4(t + ls[j] * 4));
    } else {  // defensive fallback (statistically unreachable)
        int fb = *flag;
        for (int n = tid; n < N; n += 256)
            if (maskbit(mask, fb, (size_t)s * N + n)) upd(ld4(t + n * 4));
    }
    __shared__ float sm[4][256];
    __shared__ float sl[4][256];
#pragma unroll
    for (int h2 = 0; h2 < 4; ++h2) { sm[h2][tid] = m4[h2]; sl[h2][tid] = l4[h2]; }
    __syncthreads();
    for (int st = 128; st >= 1; st >>= 1) {
        if (tid < st) {
#pragma unroll
            for (int h2 = 0; h2 < 4; ++h2) {
                float m1 = sm[h2][tid], m2 = sm[h2][tid + st];
                float l1 = sl[h2][tid], l2 = sl[h2][tid + st];
                float M = fmaxf(m1, m2);
                float e1 = (m1 == M) ? l1 : l1 * __expf(m1 - M);
                float e2 = (m2 == M) ? l2 : l2 * __expf(m2 - M);
                sm[h2][tid] = M; sl[h2][tid] = e1 + e2;
            }
        }
        __syncthreads();
    }
    if (tid < 4) { ml[s * 8 + tid] = sm[tid][0]; ml[s * 8 + 4 + tid] = sl[tid][0]; }
}

// weighted V accumulation: sub[s,:] += sum_n softmax * V[n,:]  (chunked for TLP)
__global__ __launch_bounds__(256) void att_pv(
    const float* __restrict__ t, const float* __restrict__ V,
    const int* __restrict__ cnt, const int* __restrict__ list,
    const void* __restrict__ mask, const int* __restrict__ flag,
    const float* __restrict__ ml, float* __restrict__ sub, int N)
{
    int s = blockIdx.y, chunk = blockIdx.x;
    int tid = threadIdx.x;
    int d = tid & 127, half = tid >> 7, hh = d >> 5;
    float m = ml[s * 8 + hh];
    float l = ml[s * 8 + 4 + hh];
    float rl = (l > 0.f) ? 1.f / l : 0.f;
    int c = cnt[s * CNTSTRIDE];
    bool uselist = (c <= CAP);
    int L = uselist ? c : N;
    int per = (L + NCHUNK - 1) / NCHUNK;
    int start = chunk * per;
    int end = min(start + per, L);
    int fb = uselist ? 0 : *flag;
    float acc = 0.f;
    for (int j = start + half; j < end; j += 2) {
        int n;
        if (uselist) {
            n = list[(size_t)s * CAP + j];
        } else {
            n = j;
            if (!maskbit(mask, fb, (size_t)s * N + n)) continue;
        }
        float w = __expf(t[n * 4 + hh] - m);
        acc += w * V[(size_t)n * HID + d];
    }
    acc *= rl;
    unsafeAtomicAdd(&sub[(size_t)s * HID + d], acc);
}

// subo = nan_to_num(sub @ wo + bo)
__global__ void wo_kernel(const float* __restrict__ sub, const float* __restrict__ wo,
                          const float* __restrict__ bo, float* __restrict__ subo)
{
    int s = blockIdx.x, c = threadIdx.x;
    __shared__ float row[HID];
    row[c] = sub[(size_t)s * HID + c];
    __syncthreads();
    float acc = bo[c];
    for (int k = 0; k < HID; ++k) acc += row[k] * wo[k * HID + c];
    subo[(size_t)s * HID + c] = nanfix(acc);
}

__global__ void sg_kernel(const float* __restrict__ subo, const float* __restrict__ q,
                          float* __restrict__ sg, int S)
{
    int s = blockIdx.x * blockDim.x + threadIdx.x;
    if (s >= S) return;
    float acc = 0.f;
    for (int k = 0; k < HID; ++k) acc += subo[(size_t)s * HID + k] * q[k];
    sg[s] = nanfix(acc * INV_SQRT_HID);
}

// top-4 (first-index tie break, desc), softmax weights, weighted sum of subo rows
__global__ void topk_kernel(const float* __restrict__ sg, const float* __restrict__ subo,
                            float* __restrict__ out)
{
    __shared__ float sv[256];
    __shared__ float rv[128];
    __shared__ int ri[128];
    __shared__ int topi[4];
    __shared__ float topv[4];
    __shared__ float tw[4];
    int tid = threadIdx.x;  // 128 threads
    sv[tid] = sg[tid];
    sv[tid + 128] = sg[tid + 128];
    __syncthreads();
    for (int it = 0; it < 4; ++it) {
        float v1 = sv[tid], v2 = sv[tid + 128];
        float bvv; int bi;
        if (v2 > v1) { bvv = v2; bi = tid + 128; } else { bvv = v1; bi = tid; }
        rv[tid] = bvv; ri[tid] = bi;
        __syncthreads();
        for (int st = 64; st >= 1; st >>= 1) {
            if (tid < st) {
                float ov = rv[tid + st]; int oi = ri[tid + st];
                if (ov > rv[tid] || (ov == rv[tid] && oi < ri[tid])) {
                    rv[tid] = ov; ri[tid] = oi;
                }
            }
            __syncthreads();
        }
        if (tid == 0) {
            topv[it] = rv[0]; topi[it] = ri[0];
            sv[ri[0]] = -INFINITY;
        }
        __syncthreads();
    }
    if (tid == 0) {
        float mx = topv[0], ssum = 0.f, e[4];
#pragma unroll
        for (int i = 0; i < 4; ++i) { e[i] = __expf(topv[i] - mx); ssum += e[i]; }
#pragma unroll
        for (int i = 0; i < 4; ++i) tw[i] = e[i] / ssum;
    }
    __syncthreads();
    float acc = 0.f;
#pragma unroll
    for (int i = 0; i < 4; ++i) acc += tw[i] * subo[(size_t)topi[i] * HID + tid];
    out[tid] = acc;
}

// ---------------------------------------------------------------------------
extern "C" void kernel_launch(void* const* d_in, const int* in_sizes, int n_in,
                              void* d_out, int out_size, void* d_ws, size_t ws_size,
                              hipStream_t stream)
{
    const int* atom_ids   = (const int*)d_in[0];
    const int* fp_ids     = (const int*)d_in[1];
    const int* ei         = (const int*)d_in[2];
    const int* eattr      = (const int*)d_in[3];
    const void* mask      = d_in[4];
    const float* emb_atom = (const float*)d_in[5];
    const float* emb_fp   = (const float*)d_in[6];
    const float* emb_bond = (const float*)d_in[7];
    const float* w_proj   = (const float*)d_in[8];
    const float* b_proj   = (const float*)d_in[9];
    const float* mlp_w1   = (const float*)d_in[10];
    const float* mlp_b1   = (const float*)d_in[11];
    const float* mlp_w2   = (const float*)d_in[12];
    const float* mlp_b2   = (const float*)d_in[13];
    const float* ln_w     = (const float*)d_in[14];
    const float* ln_b     = (const float*)d_in[15];
    const float* wq       = (const float*)d_in[16];
    const float* bq       = (const float*)d_in[17];
    const float* wk       = (const float*)d_in[18];
    const float* bk       = (const float*)d_in[19];
    const float* wvp      = (const float*)d_in[20];
    const float* bvp      = (const float*)d_in[21];
    const float* wo       = (const float*)d_in[22];
    const float* bo       = (const float*)d_in[23];
    const float* sgq      = (const float*)d_in[24];

    const int N = in_sizes[0];
    const int E = in_sizes[3];
    const int S = in_sizes[4] / N;           // 256
    const int NBM1 = in_sizes[7] / HID - 1;  // bond-id clamp limit

    char* p = (char*)d_ws;
    auto alloc = [&](size_t b) -> char* {
        char* r = p; p += (b + 255) & ~(size_t)255; return r;
    };
    float* hbuf   = (float*)alloc((size_t)N * HID * 4);
    float* abuf   = (float*)alloc((size_t)N * HID * 4);  // agg -> t1 -> K
    float* zbuf   = (float*)alloc((size_t)N * HID * 4);  // z -> V
    float* tsc    = (float*)alloc((size_t)N * 4 * 4);
    int* deg      = (int*)alloc((size_t)N * 4);
    int* rowptr   = (int*)alloc((size_t)(N + 1) * 4);
    int* fill     = (int*)alloc((size_t)N * 4);
    int* csrc     = (int*)alloc((size_t)(E + N) * 4);
    int* ceid     = (int*)alloc((size_t)(E + N) * 4);
    float* hsum   = (float*)alloc(512);
    double* stats = (double*)alloc(256);
    float* qvec   = (float*)alloc(512);
    float* mlbuf  = (float*)alloc((size_t)S * 8 * 4);
    int* cnt      = (int*)alloc((size_t)S * CNTSTRIDE * 4);
    int* flag     = (int*)alloc(256);
    int* list     = (int*)alloc((size_t)S * CAP * 4);
    float* sub    = (float*)alloc((size_t)S * HID * 4);
    float* subo   = (float*)alloc((size_t)S * HID * 4);
    float* sgsc   = (float*)alloc((size_t)S * 4);

    const int mblocks = (N + 63) / 64;

    // mask layout detection (independent of everything else)
    hipMemsetAsync(flag, 0, 4, stream);
    detect_mask<<<1, 256, 0, stream>>>(mask, 2048, flag);

    // CSR build (once; topology is h-independent)
    init_deg<<<(N + 255) / 256, 256, 0, stream>>>(deg, N);
    hist_kernel<<<(E + 255) / 256, 256, 0, stream>>>(ei, deg, E);
    scan_kernel<<<1, 1024, 0, stream>>>(deg, rowptr, N);
    hipMemsetAsync(fill, 0, (size_t)N * 4, stream);
    scatter_kernel<<<(E + N + 255) / 256, 256, 0, stream>>>(
        ei, eattr, rowptr, fill, csrc, ceid, E, N, NBM1);

    // node features: x = nan_to_num(concat(emb_atom[a], emb_fp[f]) @ w_proj + b)
    gemm128<2, false, false, true><<<mblocks, 256, 0, stream>>>(
        nullptr, nullptr, atom_ids, fp_ids, emb_atom, emb_fp,
        w_proj, b_proj, nullptr, hbuf, N, 2 * HID);

    for (int l = 0; l < 3; ++l) {
        gine_gather<<<(N * 64 + 255) / 256, 256, 0, stream>>>(
            rowptr, csrc, ceid, hbuf, emb_bond, abuf, N);
        // t1 = relu((h+agg) @ w1 + b1)   (t1 overwrites agg; row-private, safe)
        gemm128<1, true, false, false><<<mblocks, 256, 0, stream>>>(
            hbuf, abuf, nullptr, nullptr, nullptr, nullptr,
            mlp_w1 + (size_t)l * HID * HID, mlp_b1 + (size_t)l * HID,
            nullptr, abuf, N, HID);
        // z = t1 @ w2 + b2 + h
        gemm128<0, false, true, false><<<mblocks, 256, 0, stream>>>(
            abuf, nullptr, nullptr, nullptr, nullptr, nullptr,
            mlp_w2 + (size_t)l * HID * HID, mlp_b2 + (size_t)l * HID,
            hbuf, zbuf, N, HID);
        hipMemsetAsync(stats, 0, 16, stream);
        ln_stats<<<1024, 256, 0, stream>>>(zbuf, stats, N * HID / 4);
        ln_silu<<<1024, 256, 0, stream>>>(zbuf, stats, ln_w + (size_t)l * HID,
                                          ln_b + (size_t)l * HID, hbuf,
                                          N * HID / 4, N * HID);
    }

    // attention pool
    hipMemsetAsync(hsum, 0, 512, stream);
    colsum<<<256, 256, 0, stream>>>(hbuf, hsum, N);
    qproj<<<1, 128, 0, stream>>>(hsum, wq, bq, qvec, 1.0f / (float)N);
    float* Kbuf = abuf;   // t1 dead
    float* Vbuf = zbuf;   // z dead
    gemm128<0, false, false, false><<<mblocks, 256, 0, stream>>>(
        hbuf, nullptr, nullptr, nullptr, nullptr, nullptr, wk, bk, nullptr, Kbuf, N, HID);
    gemm128<0, false, false, false><<<mblocks, 256, 0, stream>>>(
        hbuf, nullptr, nullptr, nullptr, nullptr, nullptr, wvp, bvp, nullptr, Vbuf, N, HID);
    score_kernel<<<(N * 64 + 255) / 256, 256, 0, stream>>>(Kbuf, qvec, tsc, N);

    hipMemsetAsync(cnt, 0, (size_t)S * CNTSTRIDE * 4, stream);
    compact<<<dim3((N + 255) / 256, S), 256, 0, stream>>>(mask, flag, cnt, list, N);
    att_ml<<<S, 256, 0, stream>>>(tsc, cnt, list, mask, flag, mlbuf, N);
    hipMemsetAsync(sub, 0, (size_t)S * HID * 4, stream);
    att_pv<<<dim3(NCHUNK, S), 256, 0, stream>>>(tsc, Vbuf, cnt, list, mask, flag,
                                                mlbuf, sub, N);
    wo_kernel<<<S, 128, 0, stream>>>(sub, wo, bo, subo);
    sg_kernel<<<1, 256, 0, stream>>>(subo, sgq, sgsc, S);
    topk_kernel<<<1, 128, 0, stream>>>(sgsc, subo, (float*)d_out);
}

// Round 7
// 1113.336 us; speedup vs baseline: 2.0055x; 1.1043x over previous
//
#include <hip/hip_runtime.h>
#include <math.h>

#define HID 128
#define CAP 4096                          // 32 sigma above binomial mean 2500 (p=0.05, N=50k)
#define NCHUNK 8
#define NCB 256                           // colsum partial blocks
#define CNTSTRIDE 32                      // one cnt per 128B cacheline (atomic-contention fix)
#define SCORE_SCALE 0.2209708691207961f   // 1/(sqrt(32)*0.8)
#define INV_SQRT_HID 0.08838834764831845f // 1/sqrt(128)

typedef unsigned char u8;

__device__ __forceinline__ float4 ld4(const float* p) { return *(const float4*)p; }
__device__ __forceinline__ float nanfix(float v) { return (v != v) ? 0.f : v; }

// ---------------------------------------------------------------------------
// Generic f32 GEMM: C[M,128] = act(Asrc @ W[K,128] + bias) (+resid)
// AMODE: 0 = A ; 1 = A + A2 (fused GINE z=h+agg) ; 2 = concat-gather(tab1[id1],tab2[id2])
// Microtile: rows tr+16i (i<4), cols tc*4+64j (j<2).
// NOTE: A2 / resid / C are NOT __restrict__ — C may alias A2 (t1 over agg).
// ---------------------------------------------------------------------------
template<int AMODE, bool RELU, bool RESID, bool NANFIX>
__global__ __launch_bounds__(256) void gemm128(
    const float* __restrict__ A, const float* A2,
    const int* __restrict__ id1, const int* __restrict__ id2,
    const float* __restrict__ tab1, const float* __restrict__ tab2,
    const float* __restrict__ W, const float* __restrict__ bias,
    const float* resid, float* C,
    int M, int K)
{
    __shared__ float As[64][36];      // stride 36 floats = 9x16B: float4-aligned rows
    __shared__ float Ws[32][HID];
    const int tid = threadIdx.x;
    const int row0 = blockIdx.x * 64;
    const int tr = tid >> 4;          // [0,16): row group
    const int tc = tid & 15;          // [0,16): col group
    float4 acc[4][2];
#pragma unroll
    for (int i = 0; i < 4; ++i)
#pragma unroll
        for (int j = 0; j < 2; ++j) acc[i][j] = make_float4(0.f, 0.f, 0.f, 0.f);

    for (int k0 = 0; k0 < K; k0 += 32) {
        // stage A tile 64x32 (512 float4 slots / 256 thr)
#pragma unroll
        for (int i = 0; i < 2; ++i) {
            int slot = tid + i * 256;
            int r = slot >> 3;
            int kc = (slot & 7) << 2;
            int gr = row0 + r;
            float4 v = make_float4(0.f, 0.f, 0.f, 0.f);
            if (gr < M) {
                int gk = k0 + kc;
                if (AMODE == 2) {
                    if (gk < HID) v = ld4(tab1 + (size_t)id1[gr] * HID + gk);
                    else          v = ld4(tab2 + (size_t)id2[gr] * HID + (gk - HID));
                } else {
                    v = ld4(A + (size_t)gr * K + gk);
                    if (AMODE == 1) {
                        float4 w = ld4(A2 + (size_t)gr * K + gk);
                        v.x += w.x; v.y += w.y; v.z += w.z; v.w += w.w;
                    }
                }
            }
            *(float4*)&As[r][kc] = v;
        }
        // stage W tile 32x128 (1024 float4 slots / 256 thr)
#pragma unroll
        for (int i = 0; i < 4; ++i) {
            int slot = tid + i * 256;
            int kr = slot >> 5;
            int c = (slot & 31) << 2;
            *(float4*)&Ws[kr][c] = ld4(W + (size_t)(k0 + kr) * HID + c);
        }
        __syncthreads();
#pragma unroll
        for (int kk0 = 0; kk0 < 32; kk0 += 4) {
            float4 av[4];
#pragma unroll
            for (int i = 0; i < 4; ++i) av[i] = *(float4*)&As[tr + 16 * i][kk0];
#pragma unroll
            for (int t = 0; t < 4; ++t) {
                int kk = kk0 + t;
                float4 w0 = *(float4*)&Ws[kk][tc * 4];
                float4 w1 = *(float4*)&Ws[kk][tc * 4 + 64];
#pragma unroll
                for (int i = 0; i < 4; ++i) {
                    float a = (t == 0) ? av[i].x : (t == 1) ? av[i].y
                            : (t == 2) ? av[i].z : av[i].w;
                    acc[i][0].x = fmaf(a, w0.x, acc[i][0].x);
                    acc[i][0].y = fmaf(a, w0.y, acc[i][0].y);
                    acc[i][0].z = fmaf(a, w0.z, acc[i][0].z);
                    acc[i][0].w = fmaf(a, w0.w, acc[i][0].w);
                    acc[i][1].x = fmaf(a, w1.x, acc[i][1].x);
                    acc[i][1].y = fmaf(a, w1.y, acc[i][1].y);
                    acc[i][1].z = fmaf(a, w1.z, acc[i][1].z);
                    acc[i][1].w = fmaf(a, w1.w, acc[i][1].w);
                }
            }
        }
        __syncthreads();
    }
#pragma unroll
    for (int j = 0; j < 2; ++j) {
        int c0 = tc * 4 + 64 * j;
        float4 bv = ld4(bias + c0);
#pragma unroll
        for (int i = 0; i < 4; ++i) {
            int gr = row0 + tr + 16 * i;
            if (gr >= M) continue;
            float o[4] = {acc[i][j].x + bv.x, acc[i][j].y + bv.y,
                          acc[i][j].z + bv.z, acc[i][j].w + bv.w};
            if (RELU) {
#pragma unroll
                for (int q = 0; q < 4; ++q) o[q] = o[q] > 0.f ? o[q] : 0.f;
            }
            if (RESID) {
                float4 rv = ld4(resid + (size_t)gr * HID + c0);
                o[0] += rv.x; o[1] += rv.y; o[2] += rv.z; o[3] += rv.w;
            }
            if (NANFIX) {
#pragma unroll
                for (int q = 0; q < 4; ++q) o[q] = nanfix(o[q]);
            }
            *(float4*)(C + (size_t)gr * HID + c0) = make_float4(o[0], o[1], o[2], o[3]);
        }
    }
}

// ---------------------------------------------------------------------------
// CSR build (once per launch; topology is h-independent).
// ---------------------------------------------------------------------------
__global__ void init_deg(int* deg, int N)
{
    int i = blockIdx.x * 256 + threadIdx.x;
    if (i < N) deg[i] = 1;   // self-loop
}

__global__ void hist_kernel(const int* __restrict__ ei, int* deg, int E)
{
    int e = blockIdx.x * 256 + threadIdx.x;
    if (e < E) atomicAdd(&deg[ei[E + e]], 1);
}

// exclusive scan of deg[0..N) -> rowptr[0..N], single block of 1024 threads
__global__ __launch_bounds__(1024) void scan_kernel(
    const int* __restrict__ deg, int* __restrict__ rowptr, int N)
{
    const int T = 1024;
    __shared__ int part[T];
    int t = threadIdx.x;
    int chunk = (N + T - 1) / T;
    int s = t * chunk;
    int e = min(s + chunk, N);
    int sum = 0;
    for (int i = s; i < e; ++i) sum += deg[i];
    part[t] = sum;
    __syncthreads();
    for (int off = 1; off < T; off <<= 1) {
        int v = (t >= off) ? part[t - off] : 0;
        __syncthreads();
        part[t] += v;
        __syncthreads();
    }
    int run = (t == 0) ? 0 : part[t - 1];
    for (int i = s; i < e; ++i) { rowptr[i] = run; run += deg[i]; }
    if (t == 0) rowptr[N] = part[T - 1];
}

__global__ void scatter_kernel(
    const int* __restrict__ ei, const int* __restrict__ eattr,
    const int* __restrict__ rowptr, int* fill,
    int* __restrict__ csrc, int* __restrict__ ceid, int E, int N, int nbm1)
{
    int g = blockIdx.x * 256 + threadIdx.x;
    if (g >= E + N) return;
    int src, dst, eid;
    if (g < E) {
        src = ei[g]; dst = ei[E + g];
        eid = eattr[g]; eid = eid < 0 ? 0 : (eid > nbm1 ? nbm1 : eid);
    } else {
        src = dst = g - E; eid = 0;
    }
    int slot = rowptr[dst] + atomicAdd(&fill[dst], 1);
    csrc[slot] = src;
    ceid[slot] = eid;
}

// ---------------------------------------------------------------------------
// GINE aggregate, CSR gather: agg[dst] = sum_in relu(h[src] + bond[eid]).
// One wave per dst row, float2 per lane. No atomics; agg fully written.
// ---------------------------------------------------------------------------
__global__ __launch_bounds__(256) void gine_gather(
    const int* __restrict__ rowptr, const int* __restrict__ csrc,
    const int* __restrict__ ceid, const float* __restrict__ h,
    const float* __restrict__ bond, float* __restrict__ agg, int N)
{
    int wid = (blockIdx.x * 256 + threadIdx.x) >> 6;
    int lane = threadIdx.x & 63;
    if (wid >= N) return;
    int beg = rowptr[wid], end = rowptr[wid + 1];
    int d = lane * 2;
    float ax = 0.f, ay = 0.f;
    for (int e = beg; e < end; ++e) {
        int src = csrc[e];
        int eid = ceid[e];
        float2 hv = *(const float2*)(h + (size_t)src * HID + d);
        float2 bv = *(const float2*)(bond + (size_t)eid * HID + d);
        float x0 = hv.x + bv.x, x1 = hv.y + bv.y;
        ax += x0 > 0.f ? x0 : 0.f;
        ay += x1 > 0.f ? x1 : 0.f;
    }
    *(float2*)(agg + (size_t)wid * HID + d) = make_float2(ax, ay);
}

// ---------------------------------------------------------------------------
// Graph LayerNorm stats: sum and sumsq over ALL N*H elements (double accum)
// ---------------------------------------------------------------------------
__global__ __launch_bounds__(256) void ln_stats(
    const float* __restrict__ z, double* __restrict__ stats, int nvec)
{
    double s1 = 0.0, s2 = 0.0;
    for (int i = blockIdx.x * blockDim.x + threadIdx.x; i < nvec;
         i += gridDim.x * blockDim.x) {
        float4 v = ld4(z + (size_t)i * 4);
        s1 += (double)v.x + (double)v.y + (double)v.z + (double)v.w;
        s2 += (double)v.x * v.x + (double)v.y * v.y + (double)v.z * v.z + (double)v.w * v.w;
    }
#pragma unroll
    for (int off = 32; off; off >>= 1) {
        s1 += __shfl_down(s1, off);
        s2 += __shfl_down(s2, off);
    }
    __shared__ double sh[2][4];
    int wid = threadIdx.x >> 6, lane = threadIdx.x & 63;
    if (lane == 0) { sh[0][wid] = s1; sh[1][wid] = s2; }
    __syncthreads();
    if (threadIdx.x == 0) {
        double a = sh[0][0] + sh[0][1] + sh[0][2] + sh[0][3];
        double b = sh[1][0] + sh[1][1] + sh[1][2] + sh[1][3];
        unsafeAtomicAdd(&stats[0], a);
        unsafeAtomicAdd(&stats[1], b);
    }
}

__global__ __launch_bounds__(256) void ln_silu(
    const float* __restrict__ z, const double* __restrict__ stats,
    const float* __restrict__ w, const float* __restrict__ b,
    float* __restrict__ h, int nvec, int total)
{
    double mu = stats[0] / total;
    double var = stats[1] / total - mu * mu;
    float mean = (float)mu;
    float rstd = (float)(1.0 / sqrt(var + 1e-5));
    for (int i = blockIdx.x * blockDim.x + threadIdx.x; i < nvec;
         i += gridDim.x * blockDim.x) {
        float4 v = ld4(z + (size_t)i * 4);
        int c = (i & 31) * 4;
        float o[4] = {v.x, v.y, v.z, v.w};
#pragma unroll
        for (int j = 0; j < 4; ++j) {
            float t = (o[j] - mean) * rstd * w[c + j] + b[c + j];
            t = t / (1.f + __expf(-t));   // silu
            o[j] = nanfix(t);
        }
        *(float4*)(h + (size_t)i * 4) = make_float4(o[0], o[1], o[2], o[3]);
    }
}

// column partial sums of h (atomic-free; reduced in qproj)
__global__ __launch_bounds__(256) void colsum_part(
    const float* __restrict__ h, float* __restrict__ partial, int N)
{
    __shared__ float sh[HID];
    int d = threadIdx.x & 127;
    int half = threadIdx.x >> 7;
    float acc = 0.f;
    for (int r = blockIdx.x * 2 + half; r < N; r += NCB * 2)
        acc += h[(size_t)r * HID + d];
    if (half == 1) sh[d] = acc;
    __syncthreads();
    if (half == 0) partial[(size_t)blockIdx.x * HID + d] = acc + sh[d];
}

// q = (colsum/N) @ wq + bq   (single 128-vector); reduces partials first
__global__ void qproj(const float* __restrict__ partial, const float* __restrict__ wq,
                      const float* __restrict__ bq, float* __restrict__ q, float invN)
{
    __shared__ float q0[HID];
    int c = threadIdx.x;
    float s = 0.f;
    for (int b = 0; b < NCB; ++b) s += partial[(size_t)b * HID + c];
    q0[c] = s * invN;
    __syncthreads();
    float acc = bq[c];
    for (int k = 0; k < HID; ++k) acc += q0[k] * wq[k * HID + c];
    q[c] = acc;
}

// t[n,head] = dot(q_head, K[n,head]) * SCORE_SCALE
__global__ __launch_bounds__(256) void score_kernel(
    const float* __restrict__ Kb, const float* __restrict__ q,
    float* __restrict__ t, int N)
{
    int gid = blockIdx.x * 256 + threadIdx.x;
    int n = gid >> 6, lane = gid & 63;
    if (n >= N) return;
    float2 kv = *(const float2*)(Kb + (size_t)n * HID + lane * 2);
    float2 qv = *(const float2*)(q + lane * 2);
    float p = kv.x * qv.x + kv.y * qv.y;
    p += __shfl_xor(p, 1);
    p += __shfl_xor(p, 2);
    p += __shfl_xor(p, 4);
    p += __shfl_xor(p, 8);
    if ((lane & 15) == 0) t[n * 4 + (lane >> 4)] = p * SCORE_SCALE;
}

// mask layout: bit1 = float32 (word 0x3F800000 seen), bit0 = packed bytes
__global__ void detect_mask(const void* mask, int nwords, int* flag)
{
    const unsigned* m = (const unsigned*)mask;
    int f = 0;
    for (int i = threadIdx.x; i < nwords; i += blockDim.x) {
        unsigned w = m[i];
        if (w == 0x3F800000u) f |= 2;
        else if (w > 1u) f |= 1;
    }
    if (f) atomicOr(flag, f);
}

__device__ __forceinline__ bool maskbit(const void* mask, int layout, size_t idx)
{
    if (layout & 2) return ((const float*)mask)[idx] != 0.f;
    if (layout & 1) return ((const u8*)mask)[idx] != 0;
    return ((const int*)mask)[idx] != 0;
}

// ---------------------------------------------------------------------------
// per-subgraph masked-node index lists — ballot-aggregated:
// one atomic per BLOCK, cnt padded to 128B stride.
// ---------------------------------------------------------------------------
__global__ __launch_bounds__(256) void compact(
    const void* __restrict__ mask, const int* __restrict__ flag,
    int* __restrict__ cnt, int* __restrict__ list, int N)
{
    int s = blockIdx.y;
    int n = blockIdx.x * 256 + threadIdx.x;
    int layout = *flag;
    bool pred = (n < N) && maskbit(mask, layout, (size_t)s * N + n);
    unsigned long long ball = __ballot(pred);
    int lane = threadIdx.x & 63;
    int wid = threadIdx.x >> 6;
    int before = __popcll(ball & ((1ull << lane) - 1ull));
    __shared__ int wcnt[4];
    __shared__ int wbase[4];
    if (lane == 0) wcnt[wid] = __popcll(ball);
    __syncthreads();
    if (threadIdx.x == 0) {
        int c0 = wcnt[0], c1 = wcnt[1], c2 = wcnt[2], c3 = wcnt[3];
        int total = c0 + c1 + c2 + c3;
        int base = total ? atomicAdd(&cnt[s * CNTSTRIDE], total) : 0;
        wbase[0] = base;
        wbase[1] = base + c0;
        wbase[2] = base + c0 + c1;
        wbase[3] = base + c0 + c1 + c2;
    }
    __syncthreads();
    if (pred) {
        int p = wbase[wid] + before;
        if (p < CAP) list[(size_t)s * CAP + p] = n;
    }
}

// per-(subgraph,head) online softmax max m and denom l; also compacts t rows
// into tcomp[s][j] (float4) so att_pv streams instead of gathering.
__global__ __launch_bounds__(256) void att_ml(
    const float* __restrict__ t, const int* __restrict__ cnt,
    const int* __restrict__ list, const void* __restrict__ mask,
    const int* __restrict__ flag, float* __restrict__ ml,
    float* __restrict__ tcomp, int N)
{
    int s = blockIdx.x;
    int tid = threadIdx.x;
    int c = cnt[s * CNTSTRIDE];
    float m4[4] = {-INFINITY, -INFINITY, -INFINITY, -INFINITY};
    float l4[4] = {0.f, 0.f, 0.f, 0.f};
    auto upd = [&](float4 tv) {
        float vv[4] = {tv.x, tv.y, tv.z, tv.w};
#pragma unroll
        for (int h2 = 0; h2 < 4; ++h2) {
            float v = vv[h2];
            if (v > m4[h2]) {
                l4[h2] = l4[h2] * __expf(m4[h2] - v);
                m4[h2] = v;
                l4[h2] += 1.f;
            } else {
                l4[h2] += __expf(v - m4[h2]);
            }
        }
    };
    if (c <= CAP) {
        const int* ls = list + (size_t)s * CAP;
        float4* tc4 = (float4*)(tcomp + (size_t)s * CAP * 4);
        for (int j = tid; j < c; j += 256) {
            float4 tv = ld4(t + ls[j] * 4);
            tc4[j] = tv;
            upd(tv);
        }
    } else {  // defensive fallback (statistically unreachable)
        int fb = *flag;
        for (int n = tid; n < N; n += 256)
            if (maskbit(mask, fb, (size_t)s * N + n)) upd(ld4(t + n * 4));
    }
    __shared__ float sm[4][256];
    __shared__ float sl[4][256];
#pragma unroll
    for (int h2 = 0; h2 < 4; ++h2) { sm[h2][tid] = m4[h2]; sl[h2][tid] = l4[h2]; }
    __syncthreads();
    for (int st = 128; st >= 1; st >>= 1) {
        if (tid < st) {
#pragma unroll
            for (int h2 = 0; h2 < 4; ++h2) {
                float m1 = sm[h2][tid], m2 = sm[h2][tid + st];
                float l1 = sl[h2][tid], l2 = sl[h2][tid + st];
                float M = fmaxf(m1, m2);
                float e1 = (m1 == M) ? l1 : l1 * __expf(m1 - M);
                float e2 = (m2 == M) ? l2 : l2 * __expf(m2 - M);
                sm[h2][tid] = M; sl[h2][tid] = e1 + e2;
            }
        }
        __syncthreads();
    }
    if (tid < 4) { ml[s * 8 + tid] = sm[tid][0]; ml[s * 8 + 4 + tid] = sl[tid][0]; }
}

// weighted V accumulation: sub[s,:] += sum_n softmax * V[n,:]
// Unroll-4 with batched independent loads (MLP); t from compacted stream.
__global__ __launch_bounds__(256) void att_pv(
    const float* __restrict__ t, const float* __restrict__ tcomp,
    const float* __restrict__ V,
    const int* __restrict__ cnt, const int* __restrict__ list,
    const void* __restrict__ mask, const int* __restrict__ flag,
    const float* __restrict__ ml, float* __restrict__ sub, int N)
{
    int s = blockIdx.y, chunk = blockIdx.x;
    int tid = threadIdx.x;
    int d = tid & 127, half = tid >> 7, hh = d >> 5;
    float m = ml[s * 8 + hh];
    float l = ml[s * 8 + 4 + hh];
    float rl = (l > 0.f) ? 1.f / l : 0.f;
    int c = cnt[s * CNTSTRIDE];
    float acc = 0.f;
    if (c <= CAP) {
        const int* ls = list + (size_t)s * CAP;
        const float* tc = tcomp + (size_t)s * CAP * 4;
        int per = (c + NCHUNK - 1) / NCHUNK;
        int start = chunk * per;
        int end = min(start + per, c);
        int j = start + half;
        for (; j + 6 < end; j += 8) {
            int n0 = ls[j], n1 = ls[j + 2], n2 = ls[j + 4], n3 = ls[j + 6];
            float t0 = tc[j * 4 + hh];
            float t1 = tc[(j + 2) * 4 + hh];
            float t2 = tc[(j + 4) * 4 + hh];
            float t3 = tc[(j + 6) * 4 + hh];
            float v0 = V[(size_t)n0 * HID + d];
            float v1 = V[(size_t)n1 * HID + d];
            float v2 = V[(size_t)n2 * HID + d];
            float v3 = V[(size_t)n3 * HID + d];
            acc += __expf(t0 - m) * v0 + __expf(t1 - m) * v1
                 + __expf(t2 - m) * v2 + __expf(t3 - m) * v3;
        }
        for (; j < end; j += 2) {
            int n = ls[j];
            acc += __expf(tc[j * 4 + hh] - m) * V[(size_t)n * HID + d];
        }
    } else {  // defensive fallback
        int fb = *flag;
        int per = (N + NCHUNK - 1) / NCHUNK;
        int start = chunk * per, end = min(start + per, N);
        for (int n = start + half; n < end; n += 2) {
            if (!maskbit(mask, fb, (size_t)s * N + n)) continue;
            acc += __expf(t[n * 4 + hh] - m) * V[(size_t)n * HID + d];
        }
    }
    unsafeAtomicAdd(&sub[(size_t)s * HID + d], acc * rl);
}

// subo = nan_to_num(sub @ wo + bo)
__global__ void wo_kernel(const float* __restrict__ sub, const float* __restrict__ wo,
                          const float* __restrict__ bo, float* __restrict__ subo)
{
    int s = blockIdx.x, c = threadIdx.x;
    __shared__ float row[HID];
    row[c] = sub[(size_t)s * HID + c];
    __syncthreads();
    float acc = bo[c];
    for (int k = 0; k < HID; ++k) acc += row[k] * wo[k * HID + c];
    subo[(size_t)s * HID + c] = nanfix(acc);
}

__global__ void sg_kernel(const float* __restrict__ subo, const float* __restrict__ q,
                          float* __restrict__ sg, int S)
{
    int s = blockIdx.x * blockDim.x + threadIdx.x;
    if (s >= S) return;
    float acc = 0.f;
    for (int k = 0; k < HID; ++k) acc += subo[(size_t)s * HID + k] * q[k];
    sg[s] = nanfix(acc * INV_SQRT_HID);
}

// top-4 (first-index tie break, desc), softmax weights, weighted sum of subo rows
__global__ void topk_kernel(const float* __restrict__ sg, const float* __restrict__ subo,
                            float* __restrict__ out)
{
    __shared__ float sv[256];
    __shared__ float rv[128];
    __shared__ int ri[128];
    __shared__ int topi[4];
    __shared__ float topv[4];
    __shared__ float tw[4];
    int tid = threadIdx.x;  // 128 threads
    sv[tid] = sg[tid];
    sv[tid + 128] = sg[tid + 128];
    __syncthreads();
    for (int it = 0; it < 4; ++it) {
        float v1 = sv[tid], v2 = sv[tid + 128];
        float bvv; int bi;
        if (v2 > v1) { bvv = v2; bi = tid + 128; } else { bvv = v1; bi = tid; }
        rv[tid] = bvv; ri[tid] = bi;
        __syncthreads();
        for (int st = 64; st >= 1; st >>= 1) {
            if (tid < st) {
                float ov = rv[tid + st]; int oi = ri[tid + st];
                if (ov > rv[tid] || (ov == rv[tid] && oi < ri[tid])) {
                    rv[tid] = ov; ri[tid] = oi;
                }
            }
            __syncthreads();
        }
        if (tid == 0) {
            topv[it] = rv[0]; topi[it] = ri[0];
            sv[ri[0]] = -INFINITY;
        }
        __syncthreads();
    }
    if (tid == 0) {
        float mx = topv[0], ssum = 0.f, e[4];
#pragma unroll
        for (int i = 0; i < 4; ++i) { e[i] = __expf(topv[i] - mx); ssum += e[i]; }
#pragma unroll
        for (int i = 0; i < 4; ++i) tw[i] = e[i] / ssum;
    }
    __syncthreads();
    float acc = 0.f;
#pragma unroll
    for (int i = 0; i < 4; ++i) acc += tw[i] * subo[(size_t)topi[i] * HID + tid];
    out[tid] = acc;
}

// ---------------------------------------------------------------------------
extern "C" void kernel_launch(void* const* d_in, const int* in_sizes, int n_in,
                              void* d_out, int out_size, void* d_ws, size_t ws_size,
                              hipStream_t stream)
{
    const int* atom_ids   = (const int*)d_in[0];
    const int* fp_ids     = (const int*)d_in[1];
    const int* ei         = (const int*)d_in[2];
    const int* eattr      = (const int*)d_in[3];
    const void* mask      = d_in[4];
    const float* emb_atom = (const float*)d_in[5];
    const float* emb_fp   = (const float*)d_in[6];
    const float* emb_bond = (const float*)d_in[7];
    const float* w_proj   = (const float*)d_in[8];
    const float* b_proj   = (const float*)d_in[9];
    const float* mlp_w1   = (const float*)d_in[10];
    const float* mlp_b1   = (const float*)d_in[11];
    const float* mlp_w2   = (const float*)d_in[12];
    const float* mlp_b2   = (const float*)d_in[13];
    const float* ln_w     = (const float*)d_in[14];
    const float* ln_b     = (const float*)d_in[15];
    const float* wq       = (const float*)d_in[16];
    const float* bq       = (const float*)d_in[17];
    const float* wk       = (const float*)d_in[18];
    const float* bk       = (const float*)d_in[19];
    const float* wvp      = (const float*)d_in[20];
    const float* bvp      = (const float*)d_in[21];
    const float* wo       = (const float*)d_in[22];
    const float* bo       = (const float*)d_in[23];
    const float* sgq      = (const float*)d_in[24];

    const int N = in_sizes[0];
    const int E = in_sizes[3];
    const int S = in_sizes[4] / N;           // 256
    const int NBM1 = in_sizes[7] / HID - 1;  // bond-id clamp limit

    char* p = (char*)d_ws;
    auto alloc = [&](size_t b) -> char* {
        char* r = p; p += (b + 255) & ~(size_t)255; return r;
    };
    float* hbuf   = (float*)alloc((size_t)N * HID * 4);
    float* abuf   = (float*)alloc((size_t)N * HID * 4);  // agg -> t1 -> K
    float* zbuf   = (float*)alloc((size_t)N * HID * 4);  // z -> V
    float* tsc    = (float*)alloc((size_t)N * 4 * 4);
    int* deg      = (int*)alloc((size_t)N * 4);
    int* rowptr   = (int*)alloc((size_t)(N + 1) * 4);
    int* fill     = (int*)alloc((size_t)N * 4);
    int* csrc     = (int*)alloc((size_t)(E + N) * 4);
    int* ceid     = (int*)alloc((size_t)(E + N) * 4);
    float* partial= (float*)alloc((size_t)NCB * HID * 4);
    double* stats = (double*)alloc(256);
    float* qvec   = (float*)alloc(512);
    float* mlbuf  = (float*)alloc((size_t)S * 8 * 4);
    int* cnt      = (int*)alloc((size_t)S * CNTSTRIDE * 4);
    int* flag     = (int*)alloc(256);
    int* list     = (int*)alloc((size_t)S * CAP * 4);
    float* tcomp  = (float*)alloc((size_t)S * CAP * 4 * 4);
    float* sub    = (float*)alloc((size_t)S * HID * 4);
    float* subo   = (float*)alloc((size_t)S * HID * 4);
    float* sgsc   = (float*)alloc((size_t)S * 4);

    const int mblocks = (N + 63) / 64;

    // mask layout detection (independent of everything else)
    hipMemsetAsync(flag, 0, 4, stream);
    detect_mask<<<1, 256, 0, stream>>>(mask, 2048, flag);

    // CSR build (once; topology is h-independent)
    init_deg<<<(N + 255) / 256, 256, 0, stream>>>(deg, N);
    hist_kernel<<<(E + 255) / 256, 256, 0, stream>>>(ei, deg, E);
    scan_kernel<<<1, 1024, 0, stream>>>(deg, rowptr, N);
    hipMemsetAsync(fill, 0, (size_t)N * 4, stream);
    scatter_kernel<<<(E + N + 255) / 256, 256, 0, stream>>>(
        ei, eattr, rowptr, fill, csrc, ceid, E, N, NBM1);

    // node features: x = nan_to_num(concat(emb_atom[a], emb_fp[f]) @ w_proj + b)
    gemm128<2, false, false, true><<<mblocks, 256, 0, stream>>>(
        nullptr, nullptr, atom_ids, fp_ids, emb_atom, emb_fp,
        w_proj, b_proj, nullptr, hbuf, N, 2 * HID);

    for (int l = 0; l < 3; ++l) {
        gine_gather<<<(N * 64 + 255) / 256, 256, 0, stream>>>(
            rowptr, csrc, ceid, hbuf, emb_bond, abuf, N);
        // t1 = relu((h+agg) @ w1 + b1)   (t1 overwrites agg; row-private, safe)
        gemm128<1, true, false, false><<<mblocks, 256, 0, stream>>>(
            hbuf, abuf, nullptr, nullptr, nullptr, nullptr,
            mlp_w1 + (size_t)l * HID * HID, mlp_b1 + (size_t)l * HID,
            nullptr, abuf, N, HID);
        // z = t1 @ w2 + b2 + h
        gemm128<0, false, true, false><<<mblocks, 256, 0, stream>>>(
            abuf, nullptr, nullptr, nullptr, nullptr, nullptr,
            mlp_w2 + (size_t)l * HID * HID, mlp_b2 + (size_t)l * HID,
            hbuf, zbuf, N, HID);
        hipMemsetAsync(stats, 0, 16, stream);
        ln_stats<<<512, 256, 0, stream>>>(zbuf, stats, N * HID / 4);
        ln_silu<<<1024, 256, 0, stream>>>(zbuf, stats, ln_w + (size_t)l * HID,
                                          ln_b + (size_t)l * HID, hbuf,
                                          N * HID / 4, N * HID);
    }

    // attention pool
    colsum_part<<<NCB, 256, 0, stream>>>(hbuf, partial, N);
    qproj<<<1, 128, 0, stream>>>(partial, wq, bq, qvec, 1.0f / (float)N);
    float* Kbuf = abuf;   // t1 dead
    float* Vbuf = zbuf;   // z dead
    gemm128<0, false, false, false><<<mblocks, 256, 0, stream>>>(
        hbuf, nullptr, nullptr, nullptr, nullptr, nullptr, wk, bk, nullptr, Kbuf, N, HID);
    gemm128<0, false, false, false><<<mblocks, 256, 0, stream>>>(
        hbuf, nullptr, nullptr, nullptr, nullptr, nullptr, wvp, bvp, nullptr, Vbuf, N, HID);
    score_kernel<<<(N * 64 + 255) / 256, 256, 0, stream>>>(Kbuf, qvec, tsc, N);

    hipMemsetAsync(cnt, 0, (size_t)S * CNTSTRIDE * 4, stream);
    compact<<<dim3((N + 255) / 256, S), 256, 0, stream>>>(mask, flag, cnt, list, N);
    att_ml<<<S, 256, 0, stream>>>(tsc, cnt, list, mask, flag, mlbuf, tcomp, N);
    hipMemsetAsync(sub, 0, (size_t)S * HID * 4, stream);
    att_pv<<<dim3(NCHUNK, S), 256, 0, stream>>>(tsc, tcomp, Vbuf, cnt, list, mask,
                                                flag, mlbuf, sub, N);
    wo_kernel<<<S, 128, 0, stream>>>(sub, wo, bo, subo);
    sg_kernel<<<1, 256, 0, stream>>>(subo, sgq, sgsc, S);
    topk_kernel<<<1, 128, 0, stream>>>(sgsc, subo, (float*)d_out);
}

// Round 8
// 1029.778 us; speedup vs baseline: 2.1682x; 1.0811x over previous
//
#include <hip/hip_runtime.h>
#include <math.h>

#define HID 128
#define CAP 4096                          // 32 sigma above binomial mean 2500 (p=0.05, N=50k)
#define NCHUNK 8
#define NCB 256                           // colsum partial blocks
#define CNTSTRIDE 32                      // one cnt per 128B cacheline (atomic-contention fix)
#define SCORE_SCALE 0.2209708691207961f   // 1/(sqrt(32)*0.8)
#define INV_SQRT_HID 0.08838834764831845f // 1/sqrt(128)

typedef unsigned char u8;

__device__ __forceinline__ float4 ld4(const float* p) { return *(const float4*)p; }
__device__ __forceinline__ float nanfix(float v) { return (v != v) ? 0.f : v; }

// ---------------------------------------------------------------------------
// Generic f32 GEMM: C[M,128] = act(Asrc @ W[K,128] + bias) (+resid)
// AMODE: 0 = A ; 1 = A + A2 (fused GINE z=h+agg) ; 2 = concat-gather(tab1[id1],tab2[id2])
// Microtile: rows tr+16i (i<4), cols tc*4+64j (j<2).
// NOTE: A2 / resid / C are NOT __restrict__ — C may alias A2 (t1 over agg).
// ---------------------------------------------------------------------------
template<int AMODE, bool RELU, bool RESID, bool NANFIX>
__global__ __launch_bounds__(256) void gemm128(
    const float* __restrict__ A, const float* A2,
    const int* __restrict__ id1, const int* __restrict__ id2,
    const float* __restrict__ tab1, const float* __restrict__ tab2,
    const float* __restrict__ W, const float* __restrict__ bias,
    const float* resid, float* C,
    int M, int K)
{
    __shared__ float As[64][36];      // stride 36 floats = 9x16B: float4-aligned rows
    __shared__ float Ws[32][HID];
    const int tid = threadIdx.x;
    const int row0 = blockIdx.x * 64;
    const int tr = tid >> 4;          // [0,16): row group
    const int tc = tid & 15;          // [0,16): col group
    float4 acc[4][2];
#pragma unroll
    for (int i = 0; i < 4; ++i)
#pragma unroll
        for (int j = 0; j < 2; ++j) acc[i][j] = make_float4(0.f, 0.f, 0.f, 0.f);

    for (int k0 = 0; k0 < K; k0 += 32) {
        // stage A tile 64x32 (512 float4 slots / 256 thr)
#pragma unroll
        for (int i = 0; i < 2; ++i) {
            int slot = tid + i * 256;
            int r = slot >> 3;
            int kc = (slot & 7) << 2;
            int gr = row0 + r;
            float4 v = make_float4(0.f, 0.f, 0.f, 0.f);
            if (gr < M) {
                int gk = k0 + kc;
                if (AMODE == 2) {
                    if (gk < HID) v = ld4(tab1 + (size_t)id1[gr] * HID + gk);
                    else          v = ld4(tab2 + (size_t)id2[gr] * HID + (gk - HID));
                } else {
                    v = ld4(A + (size_t)gr * K + gk);
                    if (AMODE == 1) {
                        float4 w = ld4(A2 + (size_t)gr * K + gk);
                        v.x += w.x; v.y += w.y; v.z += w.z; v.w += w.w;
                    }
                }
            }
            *(float4*)&As[r][kc] = v;
        }
        // stage W tile 32x128 (1024 float4 slots / 256 thr)
#pragma unroll
        for (int i = 0; i < 4; ++i) {
            int slot = tid + i * 256;
            int kr = slot >> 5;
            int c = (slot & 31) << 2;
            *(float4*)&Ws[kr][c] = ld4(W + (size_t)(k0 + kr) * HID + c);
        }
        __syncthreads();
#pragma unroll
        for (int kk0 = 0; kk0 < 32; kk0 += 4) {
            float4 av[4];
#pragma unroll
            for (int i = 0; i < 4; ++i) av[i] = *(float4*)&As[tr + 16 * i][kk0];
#pragma unroll
            for (int t = 0; t < 4; ++t) {
                int kk = kk0 + t;
                float4 w0 = *(float4*)&Ws[kk][tc * 4];
                float4 w1 = *(float4*)&Ws[kk][tc * 4 + 64];
#pragma unroll
                for (int i = 0; i < 4; ++i) {
                    float a = (t == 0) ? av[i].x : (t == 1) ? av[i].y
                            : (t == 2) ? av[i].z : av[i].w;
                    acc[i][0].x = fmaf(a, w0.x, acc[i][0].x);
                    acc[i][0].y = fmaf(a, w0.y, acc[i][0].y);
                    acc[i][0].z = fmaf(a, w0.z, acc[i][0].z);
                    acc[i][0].w = fmaf(a, w0.w, acc[i][0].w);
                    acc[i][1].x = fmaf(a, w1.x, acc[i][1].x);
                    acc[i][1].y = fmaf(a, w1.y, acc[i][1].y);
                    acc[i][1].z = fmaf(a, w1.z, acc[i][1].z);
                    acc[i][1].w = fmaf(a, w1.w, acc[i][1].w);
                }
            }
        }
        __syncthreads();
    }
#pragma unroll
    for (int j = 0; j < 2; ++j) {
        int c0 = tc * 4 + 64 * j;
        float4 bv = ld4(bias + c0);
#pragma unroll
        for (int i = 0; i < 4; ++i) {
            int gr = row0 + tr + 16 * i;
            if (gr >= M) continue;
            float o[4] = {acc[i][j].x + bv.x, acc[i][j].y + bv.y,
                          acc[i][j].z + bv.z, acc[i][j].w + bv.w};
            if (RELU) {
#pragma unroll
                for (int q = 0; q < 4; ++q) o[q] = o[q] > 0.f ? o[q] : 0.f;
            }
            if (RESID) {
                float4 rv = ld4(resid + (size_t)gr * HID + c0);
                o[0] += rv.x; o[1] += rv.y; o[2] += rv.z; o[3] += rv.w;
            }
            if (NANFIX) {
#pragma unroll
                for (int q = 0; q < 4; ++q) o[q] = nanfix(o[q]);
            }
            *(float4*)(C + (size_t)gr * HID + c0) = make_float4(o[0], o[1], o[2], o[3]);
        }
    }
}

// ---------------------------------------------------------------------------
// CSR build (once per launch; topology is h-independent).
// ---------------------------------------------------------------------------
__global__ void init_deg(int* deg, int N)
{
    int i = blockIdx.x * 256 + threadIdx.x;
    if (i < N) deg[i] = 1;   // self-loop
}

__global__ void hist_kernel(const int* __restrict__ ei, int* deg, int E)
{
    int e = blockIdx.x * 256 + threadIdx.x;
    if (e < E) atomicAdd(&deg[ei[E + e]], 1);
}

// exclusive scan of deg[0..N) -> rowptr[0..N], single block of 1024 threads
__global__ __launch_bounds__(1024) void scan_kernel(
    const int* __restrict__ deg, int* __restrict__ rowptr, int N)
{
    const int T = 1024;
    __shared__ int part[T];
    int t = threadIdx.x;
    int chunk = (N + T - 1) / T;
    int s = t * chunk;
    int e = min(s + chunk, N);
    int sum = 0;
    for (int i = s; i < e; ++i) sum += deg[i];
    part[t] = sum;
    __syncthreads();
    for (int off = 1; off < T; off <<= 1) {
        int v = (t >= off) ? part[t - off] : 0;
        __syncthreads();
        part[t] += v;
        __syncthreads();
    }
    int run = (t == 0) ? 0 : part[t - 1];
    for (int i = s; i < e; ++i) { rowptr[i] = run; run += deg[i]; }
    if (t == 0) rowptr[N] = part[T - 1];
}

__global__ void scatter_kernel(
    const int* __restrict__ ei, const int* __restrict__ eattr,
    const int* __restrict__ rowptr, int* fill,
    int* __restrict__ csrc, int* __restrict__ ceid, int E, int N, int nbm1)
{
    int g = blockIdx.x * 256 + threadIdx.x;
    if (g >= E + N) return;
    int src, dst, eid;
    if (g < E) {
        src = ei[g]; dst = ei[E + g];
        eid = eattr[g]; eid = eid < 0 ? 0 : (eid > nbm1 ? nbm1 : eid);
    } else {
        src = dst = g - E; eid = 0;
    }
    int slot = rowptr[dst] + atomicAdd(&fill[dst], 1);
    csrc[slot] = src;
    ceid[slot] = eid;
}

// ---------------------------------------------------------------------------
// GINE aggregate, CSR gather: agg[dst] = sum_in relu(h[src] + bond[eid]).
// One wave per dst row, float2 per lane. 4-deep edge unroll: 4 independent
// h[src] loads in flight per wave (latency-bound fix; was 1-deep chain).
// ---------------------------------------------------------------------------
__global__ __launch_bounds__(256) void gine_gather(
    const int* __restrict__ rowptr, const int* __restrict__ csrc,
    const int* __restrict__ ceid, const float* __restrict__ h,
    const float* __restrict__ bond, float* __restrict__ agg, int N)
{
    int wid = (blockIdx.x * 256 + threadIdx.x) >> 6;
    int lane = threadIdx.x & 63;
    if (wid >= N) return;
    int beg = rowptr[wid], end = rowptr[wid + 1];
    int d = lane * 2;
    float ax = 0.f, ay = 0.f;
    int e = beg;
    for (; e + 3 < end; e += 4) {
        int s0 = csrc[e],     s1 = csrc[e + 1];
        int s2 = csrc[e + 2], s3 = csrc[e + 3];
        int b0 = ceid[e],     b1 = ceid[e + 1];
        int b2 = ceid[e + 2], b3 = ceid[e + 3];
        float2 h0 = *(const float2*)(h + (size_t)s0 * HID + d);
        float2 h1 = *(const float2*)(h + (size_t)s1 * HID + d);
        float2 h2 = *(const float2*)(h + (size_t)s2 * HID + d);
        float2 h3 = *(const float2*)(h + (size_t)s3 * HID + d);
        float2 e0 = *(const float2*)(bond + (size_t)b0 * HID + d);
        float2 e1 = *(const float2*)(bond + (size_t)b1 * HID + d);
        float2 e2 = *(const float2*)(bond + (size_t)b2 * HID + d);
        float2 e3 = *(const float2*)(bond + (size_t)b3 * HID + d);
        float x;
        x = h0.x + e0.x; ax += x > 0.f ? x : 0.f;
        x = h0.y + e0.y; ay += x > 0.f ? x : 0.f;
        x = h1.x + e1.x; ax += x > 0.f ? x : 0.f;
        x = h1.y + e1.y; ay += x > 0.f ? x : 0.f;
        x = h2.x + e2.x; ax += x > 0.f ? x : 0.f;
        x = h2.y + e2.y; ay += x > 0.f ? x : 0.f;
        x = h3.x + e3.x; ax += x > 0.f ? x : 0.f;
        x = h3.y + e3.y; ay += x > 0.f ? x : 0.f;
    }
    for (; e < end; ++e) {
        int src = csrc[e];
        int eid = ceid[e];
        float2 hv = *(const float2*)(h + (size_t)src * HID + d);
        float2 bv = *(const float2*)(bond + (size_t)eid * HID + d);
        float x0 = hv.x + bv.x, x1 = hv.y + bv.y;
        ax += x0 > 0.f ? x0 : 0.f;
        ay += x1 > 0.f ? x1 : 0.f;
    }
    *(float2*)(agg + (size_t)wid * HID + d) = make_float2(ax, ay);
}

// ---------------------------------------------------------------------------
// Graph LayerNorm stats: sum and sumsq over ALL N*H elements (double accum)
// ---------------------------------------------------------------------------
__global__ __launch_bounds__(256) void ln_stats(
    const float* __restrict__ z, double* __restrict__ stats, int nvec)
{
    double s1 = 0.0, s2 = 0.0;
    for (int i = blockIdx.x * blockDim.x + threadIdx.x; i < nvec;
         i += gridDim.x * blockDim.x) {
        float4 v = ld4(z + (size_t)i * 4);
        s1 += (double)v.x + (double)v.y + (double)v.z + (double)v.w;
        s2 += (double)v.x * v.x + (double)v.y * v.y + (double)v.z * v.z + (double)v.w * v.w;
    }
#pragma unroll
    for (int off = 32; off; off >>= 1) {
        s1 += __shfl_down(s1, off);
        s2 += __shfl_down(s2, off);
    }
    __shared__ double sh[2][4];
    int wid = threadIdx.x >> 6, lane = threadIdx.x & 63;
    if (lane == 0) { sh[0][wid] = s1; sh[1][wid] = s2; }
    __syncthreads();
    if (threadIdx.x == 0) {
        double a = sh[0][0] + sh[0][1] + sh[0][2] + sh[0][3];
        double b = sh[1][0] + sh[1][1] + sh[1][2] + sh[1][3];
        unsafeAtomicAdd(&stats[0], a);
        unsafeAtomicAdd(&stats[1], b);
    }
}

__global__ __launch_bounds__(256) void ln_silu(
    const float* __restrict__ z, const double* __restrict__ stats,
    const float* __restrict__ w, const float* __restrict__ b,
    float* __restrict__ h, int nvec, int total)
{
    double mu = stats[0] / total;
    double var = stats[1] / total - mu * mu;
    float mean = (float)mu;
    float rstd = (float)(1.0 / sqrt(var + 1e-5));
    for (int i = blockIdx.x * blockDim.x + threadIdx.x; i < nvec;
         i += gridDim.x * blockDim.x) {
        float4 v = ld4(z + (size_t)i * 4);
        int c = (i & 31) * 4;
        float o[4] = {v.x, v.y, v.z, v.w};
#pragma unroll
        for (int j = 0; j < 4; ++j) {
            float t = (o[j] - mean) * rstd * w[c + j] + b[c + j];
            t = t / (1.f + __expf(-t));   // silu
            o[j] = nanfix(t);
        }
        *(float4*)(h + (size_t)i * 4) = make_float4(o[0], o[1], o[2], o[3]);
    }
}

// column partial sums of h (atomic-free; reduced in qproj)
__global__ __launch_bounds__(256) void colsum_part(
    const float* __restrict__ h, float* __restrict__ partial, int N)
{
    __shared__ float sh[HID];
    int d = threadIdx.x & 127;
    int half = threadIdx.x >> 7;
    float acc = 0.f;
    for (int r = blockIdx.x * 2 + half; r < N; r += NCB * 2)
        acc += h[(size_t)r * HID + d];
    if (half == 1) sh[d] = acc;
    __syncthreads();
    if (half == 0) partial[(size_t)blockIdx.x * HID + d] = acc + sh[d];
}

// q = (colsum/N) @ wq + bq   (single 128-vector); reduces partials first
__global__ void qproj(const float* __restrict__ partial, const float* __restrict__ wq,
                      const float* __restrict__ bq, float* __restrict__ q, float invN)
{
    __shared__ float q0[HID];
    int c = threadIdx.x;
    float s = 0.f;
    for (int b = 0; b < NCB; ++b) s += partial[(size_t)b * HID + c];
    q0[c] = s * invN;
    __syncthreads();
    float acc = bq[c];
    for (int k = 0; k < HID; ++k) acc += q0[k] * wq[k * HID + c];
    q[c] = acc;
}

// t[n,head] = dot(q_head, K[n,head]) * SCORE_SCALE
__global__ __launch_bounds__(256) void score_kernel(
    const float* __restrict__ Kb, const float* __restrict__ q,
    float* __restrict__ t, int N)
{
    int gid = blockIdx.x * 256 + threadIdx.x;
    int n = gid >> 6, lane = gid & 63;
    if (n >= N) return;
    float2 kv = *(const float2*)(Kb + (size_t)n * HID + lane * 2);
    float2 qv = *(const float2*)(q + lane * 2);
    float p = kv.x * qv.x + kv.y * qv.y;
    p += __shfl_xor(p, 1);
    p += __shfl_xor(p, 2);
    p += __shfl_xor(p, 4);
    p += __shfl_xor(p, 8);
    if ((lane & 15) == 0) t[n * 4 + (lane >> 4)] = p * SCORE_SCALE;
}

// mask layout: bit1 = float32 (word 0x3F800000 seen), bit0 = packed bytes
__global__ void detect_mask(const void* mask, int nwords, int* flag)
{
    const unsigned* m = (const unsigned*)mask;
    int f = 0;
    for (int i = threadIdx.x; i < nwords; i += blockDim.x) {
        unsigned w = m[i];
        if (w == 0x3F800000u) f |= 2;
        else if (w > 1u) f |= 1;
    }
    if (f) atomicOr(flag, f);
}

__device__ __forceinline__ bool maskbit(const void* mask, int layout, size_t idx)
{
    if (layout & 2) return ((const float*)mask)[idx] != 0.f;
    if (layout & 1) return ((const u8*)mask)[idx] != 0;
    return ((const int*)mask)[idx] != 0;
}

// ---------------------------------------------------------------------------
// per-subgraph masked-node index lists — ballot-aggregated:
// one atomic per BLOCK, cnt padded to 128B stride.
// ---------------------------------------------------------------------------
__global__ __launch_bounds__(256) void compact(
    const void* __restrict__ mask, const int* __restrict__ flag,
    int* __restrict__ cnt, int* __restrict__ list, int N)
{
    int s = blockIdx.y;
    int n = blockIdx.x * 256 + threadIdx.x;
    int layout = *flag;
    bool pred = (n < N) && maskbit(mask, layout, (size_t)s * N + n);
    unsigned long long ball = __ballot(pred);
    int lane = threadIdx.x & 63;
    int wid = threadIdx.x >> 6;
    int before = __popcll(ball & ((1ull << lane) - 1ull));
    __shared__ int wcnt[4];
    __shared__ int wbase[4];
    if (lane == 0) wcnt[wid] = __popcll(ball);
    __syncthreads();
    if (threadIdx.x == 0) {
        int c0 = wcnt[0], c1 = wcnt[1], c2 = wcnt[2], c3 = wcnt[3];
        int total = c0 + c1 + c2 + c3;
        int base = total ? atomicAdd(&cnt[s * CNTSTRIDE], total) : 0;
        wbase[0] = base;
        wbase[1] = base + c0;
        wbase[2] = base + c0 + c1;
        wbase[3] = base + c0 + c1 + c2;
    }
    __syncthreads();
    if (pred) {
        int p = wbase[wid] + before;
        if (p < CAP) list[(size_t)s * CAP + p] = n;
    }
}

// per-(subgraph,head) online softmax max m and denom l; also compacts t rows
// into tcomp[s][j] (float4) so att_pv streams instead of gathering.
__global__ __launch_bounds__(256) void att_ml(
    const float* __restrict__ t, const int* __restrict__ cnt,
    const int* __restrict__ list, const void* __restrict__ mask,
    const int* __restrict__ flag, float* __restrict__ ml,
    float* __restrict__ tcomp, int N)
{
    int s = blockIdx.x;
    int tid = threadIdx.x;
    int c = cnt[s * CNTSTRIDE];
    float m4[4] = {-INFINITY, -INFINITY, -INFINITY, -INFINITY};
    float l4[4] = {0.f, 0.f, 0.f, 0.f};
    auto upd = [&](float4 tv) {
        float vv[4] = {tv.x, tv.y, tv.z, tv.w};
#pragma unroll
        for (int h2 = 0; h2 < 4; ++h2) {
            float v = vv[h2];
            if (v > m4[h2]) {
                l4[h2] = l4[h2] * __expf(m4[h2] - v);
                m4[h2] = v;
                l4[h2] += 1.f;
            } else {
                l4[h2] += __expf(v - m4[h2]);
            }
        }
    };
    if (c <= CAP) {
        const int* ls = list + (size_t)s * CAP;
        float4* tc4 = (float4*)(tcomp + (size_t)s * CAP * 4);
        for (int j = tid; j < c; j += 256) {
            float4 tv = ld4(t + ls[j] * 4);
            tc4[j] = tv;
            upd(tv);
        }
    } else {  // defensive fallback (statistically unreachable)
        int fb = *flag;
        for (int n = tid; n < N; n += 256)
            if (maskbit(mask, fb, (size_t)s * N + n)) upd(ld4(t + n * 4));
    }
    __shared__ float sm[4][256];
    __shared__ float sl[4][256];
#pragma unroll
    for (int h2 = 0; h2 < 4; ++h2) { sm[h2][tid] = m4[h2]; sl[h2][tid] = l4[h2]; }
    __syncthreads();
    for (int st = 128; st >= 1; st >>= 1) {
        if (tid < st) {
#pragma unroll
            for (int h2 = 0; h2 < 4; ++h2) {
                float m1 = sm[h2][tid], m2 = sm[h2][tid + st];
                float l1 = sl[h2][tid], l2 = sl[h2][tid + st];
                float M = fmaxf(m1, m2);
                float e1 = (m1 == M) ? l1 : l1 * __expf(m1 - M);
                float e2 = (m2 == M) ? l2 : l2 * __expf(m2 - M);
                sm[h2][tid] = M; sl[h2][tid] = e1 + e2;
            }
        }
        __syncthreads();
    }
    if (tid < 4) { ml[s * 8 + tid] = sm[tid][0]; ml[s * 8 + 4 + tid] = sl[tid][0]; }
}

// weighted V accumulation: sub[s,:] += sum_n softmax * V[n,:]
// Unroll-4 with batched independent loads (MLP); t from compacted stream.
__global__ __launch_bounds__(256) void att_pv(
    const float* __restrict__ t, const float* __restrict__ tcomp,
    const float* __restrict__ V,
    const int* __restrict__ cnt, const int* __restrict__ list,
    const void* __restrict__ mask, const int* __restrict__ flag,
    const float* __restrict__ ml, float* __restrict__ sub, int N)
{
    int s = blockIdx.y, chunk = blockIdx.x;
    int tid = threadIdx.x;
    int d = tid & 127, half = tid >> 7, hh = d >> 5;
    float m = ml[s * 8 + hh];
    float l = ml[s * 8 + 4 + hh];
    float rl = (l > 0.f) ? 1.f / l : 0.f;
    int c = cnt[s * CNTSTRIDE];
    float acc = 0.f;
    if (c <= CAP) {
        const int* ls = list + (size_t)s * CAP;
        const float* tc = tcomp + (size_t)s * CAP * 4;
        int per = (c + NCHUNK - 1) / NCHUNK;
        int start = chunk * per;
        int end = min(start + per, c);
        int j = start + half;
        for (; j + 6 < end; j += 8) {
            int n0 = ls[j], n1 = ls[j + 2], n2 = ls[j + 4], n3 = ls[j + 6];
            float t0 = tc[j * 4 + hh];
            float t1 = tc[(j + 2) * 4 + hh];
            float t2 = tc[(j + 4) * 4 + hh];
            float t3 = tc[(j + 6) * 4 + hh];
            float v0 = V[(size_t)n0 * HID + d];
            float v1 = V[(size_t)n1 * HID + d];
            float v2 = V[(size_t)n2 * HID + d];
            float v3 = V[(size_t)n3 * HID + d];
            acc += __expf(t0 - m) * v0 + __expf(t1 - m) * v1
                 + __expf(t2 - m) * v2 + __expf(t3 - m) * v3;
        }
        for (; j < end; j += 2) {
            int n = ls[j];
            acc += __expf(tc[j * 4 + hh] - m) * V[(size_t)n * HID + d];
        }
    } else {  // defensive fallback
        int fb = *flag;
        int per = (N + NCHUNK - 1) / NCHUNK;
        int start = chunk * per, end = min(start + per, N);
        for (int n = start + half; n < end; n += 2) {
            if (!maskbit(mask, fb, (size_t)s * N + n)) continue;
            acc += __expf(t[n * 4 + hh] - m) * V[(size_t)n * HID + d];
        }
    }
    unsafeAtomicAdd(&sub[(size_t)s * HID + d], acc * rl);
}

// subo = nan_to_num(sub @ wo + bo)
__global__ void wo_kernel(const float* __restrict__ sub, const float* __restrict__ wo,
                          const float* __restrict__ bo, float* __restrict__ subo)
{
    int s = blockIdx.x, c = threadIdx.x;
    __shared__ float row[HID];
    row[c] = sub[(size_t)s * HID + c];
    __syncthreads();
    float acc = bo[c];
    for (int k = 0; k < HID; ++k) acc += row[k] * wo[k * HID + c];
    subo[(size_t)s * HID + c] = nanfix(acc);
}

__global__ void sg_kernel(const float* __restrict__ subo, const float* __restrict__ q,
                          float* __restrict__ sg, int S)
{
    int s = blockIdx.x * blockDim.x + threadIdx.x;
    if (s >= S) return;
    float acc = 0.f;
    for (int k = 0; k < HID; ++k) acc += subo[(size_t)s * HID + k] * q[k];
    sg[s] = nanfix(acc * INV_SQRT_HID);
}

// top-4 (first-index tie break, desc), softmax weights, weighted sum of subo rows
__global__ void topk_kernel(const float* __restrict__ sg, const float* __restrict__ subo,
                            float* __restrict__ out)
{
    __shared__ float sv[256];
    __shared__ float rv[128];
    __shared__ int ri[128];
    __shared__ int topi[4];
    __shared__ float topv[4];
    __shared__ float tw[4];
    int tid = threadIdx.x;  // 128 threads
    sv[tid] = sg[tid];
    sv[tid + 128] = sg[tid + 128];
    __syncthreads();
    for (int it = 0; it < 4; ++it) {
        float v1 = sv[tid], v2 = sv[tid + 128];
        float bvv; int bi;
        if (v2 > v1) { bvv = v2; bi = tid + 128; } else { bvv = v1; bi = tid; }
        rv[tid] = bvv; ri[tid] = bi;
        __syncthreads();
        for (int st = 64; st >= 1; st >>= 1) {
            if (tid < st) {
                float ov = rv[tid + st]; int oi = ri[tid + st];
                if (ov > rv[tid] || (ov == rv[tid] && oi < ri[tid])) {
                    rv[tid] = ov; ri[tid] = oi;
                }
            }
            __syncthreads();
        }
        if (tid == 0) {
            topv[it] = rv[0]; topi[it] = ri[0];
            sv[ri[0]] = -INFINITY;
        }
        __syncthreads();
    }
    if (tid == 0) {
        float mx = topv[0], ssum = 0.f, e[4];
#pragma unroll
        for (int i = 0; i < 4; ++i) { e[i] = __expf(topv[i] - mx); ssum += e[i]; }
#pragma unroll
        for (int i = 0; i < 4; ++i) tw[i] = e[i] / ssum;
    }
    __syncthreads();
    float acc = 0.f;
#pragma unroll
    for (int i = 0; i < 4; ++i) acc += tw[i] * subo[(size_t)topi[i] * HID + tid];
    out[tid] = acc;
}

// ---------------------------------------------------------------------------
extern "C" void kernel_launch(void* const* d_in, const int* in_sizes, int n_in,
                              void* d_out, int out_size, void* d_ws, size_t ws_size,
                              hipStream_t stream)
{
    const int* atom_ids   = (const int*)d_in[0];
    const int* fp_ids     = (const int*)d_in[1];
    const int* ei         = (const int*)d_in[2];
    const int* eattr      = (const int*)d_in[3];
    const void* mask      = d_in[4];
    const float* emb_atom = (const float*)d_in[5];
    const float* emb_fp   = (const float*)d_in[6];
    const float* emb_bond = (const float*)d_in[7];
    const float* w_proj   = (const float*)d_in[8];
    const float* b_proj   = (const float*)d_in[9];
    const float* mlp_w1   = (const float*)d_in[10];
    const float* mlp_b1   = (const float*)d_in[11];
    const float* mlp_w2   = (const float*)d_in[12];
    const float* mlp_b2   = (const float*)d_in[13];
    const float* ln_w     = (const float*)d_in[14];
    const float* ln_b     = (const float*)d_in[15];
    const float* wq       = (const float*)d_in[16];
    const float* bq       = (const float*)d_in[17];
    const float* wk       = (const float*)d_in[18];
    const float* bk       = (const float*)d_in[19];
    const float* wvp      = (const float*)d_in[20];
    const float* bvp      = (const float*)d_in[21];
    const float* wo       = (const float*)d_in[22];
    const float* bo       = (const float*)d_in[23];
    const float* sgq      = (const float*)d_in[24];

    const int N = in_sizes[0];
    const int E = in_sizes[3];
    const int S = in_sizes[4] / N;           // 256
    const int NBM1 = in_sizes[7] / HID - 1;  // bond-id clamp limit

    char* p = (char*)d_ws;
    auto alloc = [&](size_t b) -> char* {
        char* r = p; p += (b + 255) & ~(size_t)255; return r;
    };
    float* hbuf   = (float*)alloc((size_t)N * HID * 4);
    float* abuf   = (float*)alloc((size_t)N * HID * 4);  // agg -> t1 -> K
    float* zbuf   = (float*)alloc((size_t)N * HID * 4);  // z -> V
    float* tsc    = (float*)alloc((size_t)N * 4 * 4);
    int* deg      = (int*)alloc((size_t)N * 4);
    int* rowptr   = (int*)alloc((size_t)(N + 1) * 4);
    int* fill     = (int*)alloc((size_t)N * 4);
    int* csrc     = (int*)alloc((size_t)(E + N) * 4);
    int* ceid     = (int*)alloc((size_t)(E + N) * 4);
    float* partial= (float*)alloc((size_t)NCB * HID * 4);
    double* stats = (double*)alloc(256);
    float* qvec   = (float*)alloc(512);
    float* mlbuf  = (float*)alloc((size_t)S * 8 * 4);
    int* cnt      = (int*)alloc((size_t)S * CNTSTRIDE * 4);
    int* flag     = (int*)alloc(256);
    int* list     = (int*)alloc((size_t)S * CAP * 4);
    float* tcomp  = (float*)alloc((size_t)S * CAP * 4 * 4);
    float* sub    = (float*)alloc((size_t)S * HID * 4);
    float* subo   = (float*)alloc((size_t)S * HID * 4);
    float* sgsc   = (float*)alloc((size_t)S * 4);

    const int mblocks = (N + 63) / 64;

    // mask layout detection (independent of everything else)
    hipMemsetAsync(flag, 0, 4, stream);
    detect_mask<<<1, 256, 0, stream>>>(mask, 2048, flag);

    // CSR build (once; topology is h-independent)
    init_deg<<<(N + 255) / 256, 256, 0, stream>>>(deg, N);
    hist_kernel<<<(E + 255) / 256, 256, 0, stream>>>(ei, deg, E);
    scan_kernel<<<1, 1024, 0, stream>>>(deg, rowptr, N);
    hipMemsetAsync(fill, 0, (size_t)N * 4, stream);
    scatter_kernel<<<(E + N + 255) / 256, 256, 0, stream>>>(
        ei, eattr, rowptr, fill, csrc, ceid, E, N, NBM1);

    // node features: x = nan_to_num(concat(emb_atom[a], emb_fp[f]) @ w_proj + b)
    gemm128<2, false, false, true><<<mblocks, 256, 0, stream>>>(
        nullptr, nullptr, atom_ids, fp_ids, emb_atom, emb_fp,
        w_proj, b_proj, nullptr, hbuf, N, 2 * HID);

    for (int l = 0; l < 3; ++l) {
        gine_gather<<<(N * 64 + 255) / 256, 256, 0, stream>>>(
            rowptr, csrc, ceid, hbuf, emb_bond, abuf, N);
        // t1 = relu((h+agg) @ w1 + b1)   (t1 overwrites agg; row-private, safe)
        gemm128<1, true, false, false><<<mblocks, 256, 0, stream>>>(
            hbuf, abuf, nullptr, nullptr, nullptr, nullptr,
            mlp_w1 + (size_t)l * HID * HID, mlp_b1 + (size_t)l * HID,
            nullptr, abuf, N, HID);
        // z = t1 @ w2 + b2 + h
        gemm128<0, false, true, false><<<mblocks, 256, 0, stream>>>(
            abuf, nullptr, nullptr, nullptr, nullptr, nullptr,
            mlp_w2 + (size_t)l * HID * HID, mlp_b2 + (size_t)l * HID,
            hbuf, zbuf, N, HID);
        hipMemsetAsync(stats, 0, 16, stream);
        ln_stats<<<512, 256, 0, stream>>>(zbuf, stats, N * HID / 4);
        ln_silu<<<1024, 256, 0, stream>>>(zbuf, stats, ln_w + (size_t)l * HID,
                                          ln_b + (size_t)l * HID, hbuf,
                                          N * HID / 4, N * HID);
    }

    // attention pool
    colsum_part<<<NCB, 256, 0, stream>>>(hbuf, partial, N);
    qproj<<<1, 128, 0, stream>>>(partial, wq, bq, qvec, 1.0f / (float)N);
    float* Kbuf = abuf;   // t1 dead
    float* Vbuf = zbuf;   // z dead
    gemm128<0, false, false, false><<<mblocks, 256, 0, stream>>>(
        hbuf, nullptr, nullptr, nullptr, nullptr, nullptr, wk, bk, nullptr, Kbuf, N, HID);
    gemm128<0, false, false, false><<<mblocks, 256, 0, stream>>>(
        hbuf, nullptr, nullptr, nullptr, nullptr, nullptr, wvp, bvp, nullptr, Vbuf, N, HID);
    score_kernel<<<(N * 64 + 255) / 256, 256, 0, stream>>>(Kbuf, qvec, tsc, N);

    hipMemsetAsync(cnt, 0, (size_t)S * CNTSTRIDE * 4, stream);
    compact<<<dim3((N + 255) / 256, S), 256, 0, stream>>>(mask, flag, cnt, list, N);
    att_ml<<<S, 256, 0, stream>>>(tsc, cnt, list, mask, flag, mlbuf, tcomp, N);
    hipMemsetAsync(sub, 0, (size_t)S * HID * 4, stream);
    att_pv<<<dim3(NCHUNK, S), 256, 0, stream>>>(tsc, tcomp, Vbuf, cnt, list, mask,
                                                flag, mlbuf, sub, N);
    wo_kernel<<<S, 128, 0, stream>>>(sub, wo, bo, subo);
    sg_kernel<<<1, 256, 0, stream>>>(subo, sgq, sgsc, S);
    topk_kernel<<<1, 128, 0, stream>>>(sgsc, subo, (float*)d_out);
}

// Round 9
// 969.764 us; speedup vs baseline: 2.3024x; 1.0619x over previous
//
#include <hip/hip_runtime.h>
#include <math.h>

#define HID 128
#define CAP 4096                          // 32 sigma above binomial mean 2500 (p=0.05, N=50k)
#define NCHUNK 8
#define NCB 256                           // colsum partial blocks
#define CNTSTRIDE 32                      // one cnt per 128B cacheline (atomic-contention fix)
#define SCORE_SCALE 0.2209708691207961f   // 1/(sqrt(32)*0.8)
#define INV_SQRT_HID 0.08838834764831845f // 1/sqrt(128)

typedef unsigned char u8;

__device__ __forceinline__ float4 ld4(const float* p) { return *(const float4*)p; }
__device__ __forceinline__ float nanfix(float v) { return (v != v) ? 0.f : v; }

// ---------------------------------------------------------------------------
// Generic f32 GEMM: C[M,128] = act(Asrc @ W[K,128] + bias) (+resid)
// AMODE: 0 = A ; 1 = A + A2 (fused GINE z=h+agg) ; 2 = concat-gather(tab1[id1],tab2[id2])
// Microtile: rows tr+16i (i<4), cols tc*4+64j (j<2).
// NOTE: A2 / resid / C are NOT __restrict__ — C may alias A2 (t1 over agg).
// ---------------------------------------------------------------------------
template<int AMODE, bool RELU, bool RESID, bool NANFIX>
__global__ __launch_bounds__(256) void gemm128(
    const float* __restrict__ A, const float* A2,
    const int* __restrict__ id1, const int* __restrict__ id2,
    const float* __restrict__ tab1, const float* __restrict__ tab2,
    const float* __restrict__ W, const float* __restrict__ bias,
    const float* resid, float* C,
    int M, int K)
{
    __shared__ float As[64][36];      // stride 36 floats = 9x16B: float4-aligned rows
    __shared__ float Ws[32][HID];
    const int tid = threadIdx.x;
    const int row0 = blockIdx.x * 64;
    const int tr = tid >> 4;          // [0,16): row group
    const int tc = tid & 15;          // [0,16): col group
    float4 acc[4][2];
#pragma unroll
    for (int i = 0; i < 4; ++i)
#pragma unroll
        for (int j = 0; j < 2; ++j) acc[i][j] = make_float4(0.f, 0.f, 0.f, 0.f);

    for (int k0 = 0; k0 < K; k0 += 32) {
        // stage A tile 64x32 (512 float4 slots / 256 thr)
#pragma unroll
        for (int i = 0; i < 2; ++i) {
            int slot = tid + i * 256;
            int r = slot >> 3;
            int kc = (slot & 7) << 2;
            int gr = row0 + r;
            float4 v = make_float4(0.f, 0.f, 0.f, 0.f);
            if (gr < M) {
                int gk = k0 + kc;
                if (AMODE == 2) {
                    if (gk < HID) v = ld4(tab1 + (size_t)id1[gr] * HID + gk);
                    else          v = ld4(tab2 + (size_t)id2[gr] * HID + (gk - HID));
                } else {
                    v = ld4(A + (size_t)gr * K + gk);
                    if (AMODE == 1) {
                        float4 w = ld4(A2 + (size_t)gr * K + gk);
                        v.x += w.x; v.y += w.y; v.z += w.z; v.w += w.w;
                    }
                }
            }
            *(float4*)&As[r][kc] = v;
        }
        // stage W tile 32x128 (1024 float4 slots / 256 thr)
#pragma unroll
        for (int i = 0; i < 4; ++i) {
            int slot = tid + i * 256;
            int kr = slot >> 5;
            int c = (slot & 31) << 2;
            *(float4*)&Ws[kr][c] = ld4(W + (size_t)(k0 + kr) * HID + c);
        }
        __syncthreads();
#pragma unroll
        for (int kk0 = 0; kk0 < 32; kk0 += 4) {
            float4 av[4];
#pragma unroll
            for (int i = 0; i < 4; ++i) av[i] = *(float4*)&As[tr + 16 * i][kk0];
#pragma unroll
            for (int t = 0; t < 4; ++t) {
                int kk = kk0 + t;
                float4 w0 = *(float4*)&Ws[kk][tc * 4];
                float4 w1 = *(float4*)&Ws[kk][tc * 4 + 64];
#pragma unroll
                for (int i = 0; i < 4; ++i) {
                    float a = (t == 0) ? av[i].x : (t == 1) ? av[i].y
                            : (t == 2) ? av[i].z : av[i].w;
                    acc[i][0].x = fmaf(a, w0.x, acc[i][0].x);
                    acc[i][0].y = fmaf(a, w0.y, acc[i][0].y);
                    acc[i][0].z = fmaf(a, w0.z, acc[i][0].z);
                    acc[i][0].w = fmaf(a, w0.w, acc[i][0].w);
                    acc[i][1].x = fmaf(a, w1.x, acc[i][1].x);
                    acc[i][1].y = fmaf(a, w1.y, acc[i][1].y);
                    acc[i][1].z = fmaf(a, w1.z, acc[i][1].z);
                    acc[i][1].w = fmaf(a, w1.w, acc[i][1].w);
                }
            }
        }
        __syncthreads();
    }
#pragma unroll
    for (int j = 0; j < 2; ++j) {
        int c0 = tc * 4 + 64 * j;
        float4 bv = ld4(bias + c0);
#pragma unroll
        for (int i = 0; i < 4; ++i) {
            int gr = row0 + tr + 16 * i;
            if (gr >= M) continue;
            float o[4] = {acc[i][j].x + bv.x, acc[i][j].y + bv.y,
                          acc[i][j].z + bv.z, acc[i][j].w + bv.w};
            if (RELU) {
#pragma unroll
                for (int q = 0; q < 4; ++q) o[q] = o[q] > 0.f ? o[q] : 0.f;
            }
            if (RESID) {
                float4 rv = ld4(resid + (size_t)gr * HID + c0);
                o[0] += rv.x; o[1] += rv.y; o[2] += rv.z; o[3] += rv.w;
            }
            if (NANFIX) {
#pragma unroll
                for (int q = 0; q < 4; ++q) o[q] = nanfix(o[q]);
            }
            *(float4*)(C + (size_t)gr * HID + c0) = make_float4(o[0], o[1], o[2], o[3]);
        }
    }
}

// ---------------------------------------------------------------------------
// CSR build (once per launch; topology is h-independent).
// Hierarchical 3-kernel prefix sum (replaces 77us single-block scan).
// ---------------------------------------------------------------------------
__global__ void init_deg(int* deg, int N)
{
    int i = blockIdx.x * 256 + threadIdx.x;
    if (i < N) deg[i] = 1;   // self-loop
}

__global__ void hist_kernel(const int* __restrict__ ei, int* deg, int E)
{
    int e = blockIdx.x * 256 + threadIdx.x;
    if (e < E) atomicAdd(&deg[ei[E + e]], 1);
}

// per-block sums of deg -> bsum[blockIdx]
__global__ __launch_bounds__(256) void block_reduce(
    const int* __restrict__ deg, int* __restrict__ bsum, int N)
{
    int i = blockIdx.x * 256 + threadIdx.x;
    int v = (i < N) ? deg[i] : 0;
#pragma unroll
    for (int off = 32; off; off >>= 1) v += __shfl_down(v, off);
    __shared__ int sh[4];
    int wid = threadIdx.x >> 6, lane = threadIdx.x & 63;
    if (lane == 0) sh[wid] = v;
    __syncthreads();
    if (threadIdx.x == 0) bsum[blockIdx.x] = sh[0] + sh[1] + sh[2] + sh[3];
}

// exclusive scan of bsum[0..nb) (nb <= 256), single block of 256
__global__ __launch_bounds__(256) void scan_bsums(
    const int* __restrict__ bsum, int* __restrict__ boff, int nb)
{
    __shared__ int sh[256];
    int t = threadIdx.x;
    int v = (t < nb) ? bsum[t] : 0;
    sh[t] = v;
    __syncthreads();
    for (int off = 1; off < 256; off <<= 1) {
        int u = (t >= off) ? sh[t - off] : 0;
        __syncthreads();
        sh[t] += u;
        __syncthreads();
    }
    if (t < nb) boff[t] = sh[t] - v;   // exclusive
}

// per-block inclusive scan + block offset -> rowptr; rowptr[N] = E+N exact
__global__ __launch_bounds__(256) void block_scan_write(
    const int* __restrict__ deg, const int* __restrict__ boff,
    int* __restrict__ rowptr, int N, int E)
{
    __shared__ int sh[256];
    int t = threadIdx.x;
    int i = blockIdx.x * 256 + t;
    int v = (i < N) ? deg[i] : 0;
    sh[t] = v;
    __syncthreads();
    for (int off = 1; off < 256; off <<= 1) {
        int u = (t >= off) ? sh[t - off] : 0;
        __syncthreads();
        sh[t] += u;
        __syncthreads();
    }
    if (i < N) rowptr[i] = boff[blockIdx.x] + sh[t] - v;   // exclusive
    if (blockIdx.x == 0 && t == 0) rowptr[N] = E + N;
}

__global__ void scatter_kernel(
    const int* __restrict__ ei, const int* __restrict__ eattr,
    const int* __restrict__ rowptr, int* fill,
    int* __restrict__ csrc, int* __restrict__ ceid, int E, int N, int nbm1)
{
    int g = blockIdx.x * 256 + threadIdx.x;
    if (g >= E + N) return;
    int src, dst, eid;
    if (g < E) {
        src = ei[g]; dst = ei[E + g];
        eid = eattr[g]; eid = eid < 0 ? 0 : (eid > nbm1 ? nbm1 : eid);
    } else {
        src = dst = g - E; eid = 0;
    }
    int slot = rowptr[dst] + atomicAdd(&fill[dst], 1);
    csrc[slot] = src;
    ceid[slot] = eid;
}

// ---------------------------------------------------------------------------
// GINE aggregate, CSR gather: agg[dst] = sum_in relu(h[src] + bond[eid]).
// One wave per dst row, float2 per lane. 4-deep edge unroll (latency fix).
// ---------------------------------------------------------------------------
__global__ __launch_bounds__(256) void gine_gather(
    const int* __restrict__ rowptr, const int* __restrict__ csrc,
    const int* __restrict__ ceid, const float* __restrict__ h,
    const float* __restrict__ bond, float* __restrict__ agg, int N)
{
    int wid = (blockIdx.x * 256 + threadIdx.x) >> 6;
    int lane = threadIdx.x & 63;
    if (wid >= N) return;
    int beg = rowptr[wid], end = rowptr[wid + 1];
    int d = lane * 2;
    float ax = 0.f, ay = 0.f;
    int e = beg;
    for (; e + 3 < end; e += 4) {
        int s0 = csrc[e],     s1 = csrc[e + 1];
        int s2 = csrc[e + 2], s3 = csrc[e + 3];
        int b0 = ceid[e],     b1 = ceid[e + 1];
        int b2 = ceid[e + 2], b3 = ceid[e + 3];
        float2 h0 = *(const float2*)(h + (size_t)s0 * HID + d);
        float2 h1 = *(const float2*)(h + (size_t)s1 * HID + d);
        float2 h2 = *(const float2*)(h + (size_t)s2 * HID + d);
        float2 h3 = *(const float2*)(h + (size_t)s3 * HID + d);
        float2 e0 = *(const float2*)(bond + (size_t)b0 * HID + d);
        float2 e1 = *(const float2*)(bond + (size_t)b1 * HID + d);
        float2 e2 = *(const float2*)(bond + (size_t)b2 * HID + d);
        float2 e3 = *(const float2*)(bond + (size_t)b3 * HID + d);
        float x;
        x = h0.x + e0.x; ax += x > 0.f ? x : 0.f;
        x = h0.y + e0.y; ay += x > 0.f ? x : 0.f;
        x = h1.x + e1.x; ax += x > 0.f ? x : 0.f;
        x = h1.y + e1.y; ay += x > 0.f ? x : 0.f;
        x = h2.x + e2.x; ax += x > 0.f ? x : 0.f;
        x = h2.y + e2.y; ay += x > 0.f ? x : 0.f;
        x = h3.x + e3.x; ax += x > 0.f ? x : 0.f;
        x = h3.y + e3.y; ay += x > 0.f ? x : 0.f;
    }
    for (; e < end; ++e) {
        int src = csrc[e];
        int eid = ceid[e];
        float2 hv = *(const float2*)(h + (size_t)src * HID + d);
        float2 bv = *(const float2*)(bond + (size_t)eid * HID + d);
        float x0 = hv.x + bv.x, x1 = hv.y + bv.y;
        ax += x0 > 0.f ? x0 : 0.f;
        ay += x1 > 0.f ? x1 : 0.f;
    }
    *(float2*)(agg + (size_t)wid * HID + d) = make_float2(ax, ay);
}

// ---------------------------------------------------------------------------
// Graph LayerNorm stats: sum and sumsq over ALL N*H elements (double accum)
// ---------------------------------------------------------------------------
__global__ __launch_bounds__(256) void ln_stats(
    const float* __restrict__ z, double* __restrict__ stats, int nvec)
{
    double s1 = 0.0, s2 = 0.0;
    for (int i = blockIdx.x * blockDim.x + threadIdx.x; i < nvec;
         i += gridDim.x * blockDim.x) {
        float4 v = ld4(z + (size_t)i * 4);
        s1 += (double)v.x + (double)v.y + (double)v.z + (double)v.w;
        s2 += (double)v.x * v.x + (double)v.y * v.y + (double)v.z * v.z + (double)v.w * v.w;
    }
#pragma unroll
    for (int off = 32; off; off >>= 1) {
        s1 += __shfl_down(s1, off);
        s2 += __shfl_down(s2, off);
    }
    __shared__ double sh[2][4];
    int wid = threadIdx.x >> 6, lane = threadIdx.x & 63;
    if (lane == 0) { sh[0][wid] = s1; sh[1][wid] = s2; }
    __syncthreads();
    if (threadIdx.x == 0) {
        double a = sh[0][0] + sh[0][1] + sh[0][2] + sh[0][3];
        double b = sh[1][0] + sh[1][1] + sh[1][2] + sh[1][3];
        unsafeAtomicAdd(&stats[0], a);
        unsafeAtomicAdd(&stats[1], b);
    }
}

__global__ __launch_bounds__(256) void ln_silu(
    const float* __restrict__ z, const double* __restrict__ stats,
    const float* __restrict__ w, const float* __restrict__ b,
    float* __restrict__ h, int nvec, int total)
{
    double mu = stats[0] / total;
    double var = stats[1] / total - mu * mu;
    float mean = (float)mu;
    float rstd = (float)(1.0 / sqrt(var + 1e-5));
    for (int i = blockIdx.x * blockDim.x + threadIdx.x; i < nvec;
         i += gridDim.x * blockDim.x) {
        float4 v = ld4(z + (size_t)i * 4);
        int c = (i & 31) * 4;
        float o[4] = {v.x, v.y, v.z, v.w};
#pragma unroll
        for (int j = 0; j < 4; ++j) {
            float t = (o[j] - mean) * rstd * w[c + j] + b[c + j];
            t = t / (1.f + __expf(-t));   // silu
            o[j] = nanfix(t);
        }
        *(float4*)(h + (size_t)i * 4) = make_float4(o[0], o[1], o[2], o[3]);
    }
}

// column partial sums of h (atomic-free; reduced in qproj)
__global__ __launch_bounds__(256) void colsum_part(
    const float* __restrict__ h, float* __restrict__ partial, int N)
{
    __shared__ float sh[HID];
    int d = threadIdx.x & 127;
    int half = threadIdx.x >> 7;
    float acc = 0.f;
    for (int r = blockIdx.x * 2 + half; r < N; r += NCB * 2)
        acc += h[(size_t)r * HID + d];
    if (half == 1) sh[d] = acc;
    __syncthreads();
    if (half == 0) partial[(size_t)blockIdx.x * HID + d] = acc + sh[d];
}

// q = (colsum/N) @ wq + bq   (single 128-vector); reduces partials first
__global__ void qproj(const float* __restrict__ partial, const float* __restrict__ wq,
                      const float* __restrict__ bq, float* __restrict__ q, float invN)
{
    __shared__ float q0[HID];
    int c = threadIdx.x;
    float s = 0.f;
    for (int b = 0; b < NCB; ++b) s += partial[(size_t)b * HID + c];
    q0[c] = s * invN;
    __syncthreads();
    float acc = bq[c];
    for (int k = 0; k < HID; ++k) acc += q0[k] * wq[k * HID + c];
    q[c] = acc;
}

// t[n,head] = dot(q_head, K[n,head]) * SCORE_SCALE
__global__ __launch_bounds__(256) void score_kernel(
    const float* __restrict__ Kb, const float* __restrict__ q,
    float* __restrict__ t, int N)
{
    int gid = blockIdx.x * 256 + threadIdx.x;
    int n = gid >> 6, lane = gid & 63;
    if (n >= N) return;
    float2 kv = *(const float2*)(Kb + (size_t)n * HID + lane * 2);
    float2 qv = *(const float2*)(q + lane * 2);
    float p = kv.x * qv.x + kv.y * qv.y;
    p += __shfl_xor(p, 1);
    p += __shfl_xor(p, 2);
    p += __shfl_xor(p, 4);
    p += __shfl_xor(p, 8);
    if ((lane & 15) == 0) t[n * 4 + (lane >> 4)] = p * SCORE_SCALE;
}

// mask layout: bit1 = float32 (word 0x3F800000 seen), bit0 = packed bytes
__global__ void detect_mask(const void* mask, int nwords, int* flag)
{
    const unsigned* m = (const unsigned*)mask;
    int f = 0;
    for (int i = threadIdx.x; i < nwords; i += blockDim.x) {
        unsigned w = m[i];
        if (w == 0x3F800000u) f |= 2;
        else if (w > 1u) f |= 1;
    }
    if (f) atomicOr(flag, f);
}

__device__ __forceinline__ bool maskbit(const void* mask, int layout, size_t idx)
{
    if (layout & 2) return ((const float*)mask)[idx] != 0.f;
    if (layout & 1) return ((const u8*)mask)[idx] != 0;
    return ((const int*)mask)[idx] != 0;
}

// ---------------------------------------------------------------------------
// per-subgraph masked-node index lists — ballot-aggregated:
// one atomic per BLOCK, cnt padded to 128B stride.
// ---------------------------------------------------------------------------
__global__ __launch_bounds__(256) void compact(
    const void* __restrict__ mask, const int* __restrict__ flag,
    int* __restrict__ cnt, int* __restrict__ list, int N)
{
    int s = blockIdx.y;
    int n = blockIdx.x * 256 + threadIdx.x;
    int layout = *flag;
    bool pred = (n < N) && maskbit(mask, layout, (size_t)s * N + n);
    unsigned long long ball = __ballot(pred);
    int lane = threadIdx.x & 63;
    int wid = threadIdx.x >> 6;
    int before = __popcll(ball & ((1ull << lane) - 1ull));
    __shared__ int wcnt[4];
    __shared__ int wbase[4];
    if (lane == 0) wcnt[wid] = __popcll(ball);
    __syncthreads();
    if (threadIdx.x == 0) {
        int c0 = wcnt[0], c1 = wcnt[1], c2 = wcnt[2], c3 = wcnt[3];
        int total = c0 + c1 + c2 + c3;
        int base = total ? atomicAdd(&cnt[s * CNTSTRIDE], total) : 0;
        wbase[0] = base;
        wbase[1] = base + c0;
        wbase[2] = base + c0 + c1;
        wbase[3] = base + c0 + c1 + c2;
    }
    __syncthreads();
    if (pred) {
        int p = wbase[wid] + before;
        if (p < CAP) list[(size_t)s * CAP + p] = n;
    }
}

// per-(subgraph,head) online softmax max m and denom l; also compacts t rows
// into tcomp[s][j] (float4) so att_pv streams instead of gathering.
__global__ __launch_bounds__(256) void att_ml(
    const float* __restrict__ t, const int* __restrict__ cnt,
    const int* __restrict__ list, const void* __restrict__ mask,
    const int* __restrict__ flag, float* __restrict__ ml,
    float* __restrict__ tcomp, int N)
{
    int s = blockIdx.x;
    int tid = threadIdx.x;
    int c = cnt[s * CNTSTRIDE];
    float m4[4] = {-INFINITY, -INFINITY, -INFINITY, -INFINITY};
    float l4[4] = {0.f, 0.f, 0.f, 0.f};
    auto upd = [&](float4 tv) {
        float vv[4] = {tv.x, tv.y, tv.z, tv.w};
#pragma unroll
        for (int h2 = 0; h2 < 4; ++h2) {
            float v = vv[h2];
            if (v > m4[h2]) {
                l4[h2] = l4[h2] * __expf(m4[h2] - v);
                m4[h2] = v;
                l4[h2] += 1.f;
            } else {
                l4[h2] += __expf(v - m4[h2]);
            }
        }
    };
    if (c <= CAP) {
        const int* ls = list + (size_t)s * CAP;
        float4* tc4 = (float4*)(tcomp + (size_t)s * CAP * 4);
        for (int j = tid; j < c; j += 256) {
            float4 tv = ld4(t + ls[j] * 4);
            tc4[j] = tv;
            upd(tv);
        }
    } else {  // defensive fallback (statistically unreachable)
        int fb = *flag;
        for (int n = tid; n < N; n += 256)
            if (maskbit(mask, fb, (size_t)s * N + n)) upd(ld4(t + n * 4));
    }
    __shared__ float sm[4][256];
    __shared__ float sl[4][256];
#pragma unroll
    for (int h2 = 0; h2 < 4; ++h2) { sm[h2][tid] = m4[h2]; sl[h2][tid] = l4[h2]; }
    __syncthreads();
    for (int st = 128; st >= 1; st >>= 1) {
        if (tid < st) {
#pragma unroll
            for (int h2 = 0; h2 < 4; ++h2) {
                float m1 = sm[h2][tid], m2 = sm[h2][tid + st];
                float l1 = sl[h2][tid], l2 = sl[h2][tid + st];
                float M = fmaxf(m1, m2);
                float e1 = (m1 == M) ? l1 : l1 * __expf(m1 - M);
                float e2 = (m2 == M) ? l2 : l2 * __expf(m2 - M);
                sm[h2][tid] = M; sl[h2][tid] = e1 + e2;
            }
        }
        __syncthreads();
    }
    if (tid < 4) { ml[s * 8 + tid] = sm[tid][0]; ml[s * 8 + 4 + tid] = sl[tid][0]; }
}

// weighted V accumulation: sub[s,:] += sum_n softmax * V[n,:]
// Unroll-4 with batched independent loads (MLP); t from compacted stream.
__global__ __launch_bounds__(256) void att_pv(
    const float* __restrict__ t, const float* __restrict__ tcomp,
    const float* __restrict__ V,
    const int* __restrict__ cnt, const int* __restrict__ list,
    const void* __restrict__ mask, const int* __restrict__ flag,
    const float* __restrict__ ml, float* __restrict__ sub, int N)
{
    int s = blockIdx.y, chunk = blockIdx.x;
    int tid = threadIdx.x;
    int d = tid & 127, half = tid >> 7, hh = d >> 5;
    float m = ml[s * 8 + hh];
    float l = ml[s * 8 + 4 + hh];
    float rl = (l > 0.f) ? 1.f / l : 0.f;
    int c = cnt[s * CNTSTRIDE];
    float acc = 0.f;
    if (c <= CAP) {
        const int* ls = list + (size_t)s * CAP;
        const float* tc = tcomp + (size_t)s * CAP * 4;
        int per = (c + NCHUNK - 1) / NCHUNK;
        int start = chunk * per;
        int end = min(start + per, c);
        int j = start + half;
        for (; j + 6 < end; j += 8) {
            int n0 = ls[j], n1 = ls[j + 2], n2 = ls[j + 4], n3 = ls[j + 6];
            float t0 = tc[j * 4 + hh];
            float t1 = tc[(j + 2) * 4 + hh];
            float t2 = tc[(j + 4) * 4 + hh];
            float t3 = tc[(j + 6) * 4 + hh];
            float v0 = V[(size_t)n0 * HID + d];
            float v1 = V[(size_t)n1 * HID + d];
            float v2 = V[(size_t)n2 * HID + d];
            float v3 = V[(size_t)n3 * HID + d];
            acc += __expf(t0 - m) * v0 + __expf(t1 - m) * v1
                 + __expf(t2 - m) * v2 + __expf(t3 - m) * v3;
        }
        for (; j < end; j += 2) {
            int n = ls[j];
            acc += __expf(tc[j * 4 + hh] - m) * V[(size_t)n * HID + d];
        }
    } else {  // defensive fallback
        int fb = *flag;
        int per = (N + NCHUNK - 1) / NCHUNK;
        int start = chunk * per, end = min(start + per, N);
        for (int n = start + half; n < end; n += 2) {
            if (!maskbit(mask, fb, (size_t)s * N + n)) continue;
            acc += __expf(t[n * 4 + hh] - m) * V[(size_t)n * HID + d];
        }
    }
    unsafeAtomicAdd(&sub[(size_t)s * HID + d], acc * rl);
}

// subo = nan_to_num(sub @ wo + bo)
__global__ void wo_kernel(const float* __restrict__ sub, const float* __restrict__ wo,
                          const float* __restrict__ bo, float* __restrict__ subo)
{
    int s = blockIdx.x, c = threadIdx.x;
    __shared__ float row[HID];
    row[c] = sub[(size_t)s * HID + c];
    __syncthreads();
    float acc = bo[c];
    for (int k = 0; k < HID; ++k) acc += row[k] * wo[k * HID + c];
    subo[(size_t)s * HID + c] = nanfix(acc);
}

__global__ void sg_kernel(const float* __restrict__ subo, const float* __restrict__ q,
                          float* __restrict__ sg, int S)
{
    int s = blockIdx.x * blockDim.x + threadIdx.x;
    if (s >= S) return;
    float acc = 0.f;
    for (int k = 0; k < HID; ++k) acc += subo[(size_t)s * HID + k] * q[k];
    sg[s] = nanfix(acc * INV_SQRT_HID);
}

// top-4 (first-index tie break, desc), softmax weights, weighted sum of subo rows
__global__ void topk_kernel(const float* __restrict__ sg, const float* __restrict__ subo,
                            float* __restrict__ out)
{
    __shared__ float sv[256];
    __shared__ float rv[128];
    __shared__ int ri[128];
    __shared__ int topi[4];
    __shared__ float topv[4];
    __shared__ float tw[4];
    int tid = threadIdx.x;  // 128 threads
    sv[tid] = sg[tid];
    sv[tid + 128] = sg[tid + 128];
    __syncthreads();
    for (int it = 0; it < 4; ++it) {
        float v1 = sv[tid], v2 = sv[tid + 128];
        float bvv; int bi;
        if (v2 > v1) { bvv = v2; bi = tid + 128; } else { bvv = v1; bi = tid; }
        rv[tid] = bvv; ri[tid] = bi;
        __syncthreads();
        for (int st = 64; st >= 1; st >>= 1) {
            if (tid < st) {
                float ov = rv[tid + st]; int oi = ri[tid + st];
                if (ov > rv[tid] || (ov == rv[tid] && oi < ri[tid])) {
                    rv[tid] = ov; ri[tid] = oi;
                }
            }
            __syncthreads();
        }
        if (tid == 0) {
            topv[it] = rv[0]; topi[it] = ri[0];
            sv[ri[0]] = -INFINITY;
        }
        __syncthreads();
    }
    if (tid == 0) {
        float mx = topv[0], ssum = 0.f, e[4];
#pragma unroll
        for (int i = 0; i < 4; ++i) { e[i] = __expf(topv[i] - mx); ssum += e[i]; }
#pragma unroll
        for (int i = 0; i < 4; ++i) tw[i] = e[i] / ssum;
    }
    __syncthreads();
    float acc = 0.f;
#pragma unroll
    for (int i = 0; i < 4; ++i) acc += tw[i] * subo[(size_t)topi[i] * HID + tid];
    out[tid] = acc;
}

// ---------------------------------------------------------------------------
extern "C" void kernel_launch(void* const* d_in, const int* in_sizes, int n_in,
                              void* d_out, int out_size, void* d_ws, size_t ws_size,
                              hipStream_t stream)
{
    const int* atom_ids   = (const int*)d_in[0];
    const int* fp_ids     = (const int*)d_in[1];
    const int* ei         = (const int*)d_in[2];
    const int* eattr      = (const int*)d_in[3];
    const void* mask      = d_in[4];
    const float* emb_atom = (const float*)d_in[5];
    const float* emb_fp   = (const float*)d_in[6];
    const float* emb_bond = (const float*)d_in[7];
    const float* w_proj   = (const float*)d_in[8];
    const float* b_proj   = (const float*)d_in[9];
    const float* mlp_w1   = (const float*)d_in[10];
    const float* mlp_b1   = (const float*)d_in[11];
    const float* mlp_w2   = (const float*)d_in[12];
    const float* mlp_b2   = (const float*)d_in[13];
    const float* ln_w     = (const float*)d_in[14];
    const float* ln_b     = (const float*)d_in[15];
    const float* wq       = (const float*)d_in[16];
    const float* bq       = (const float*)d_in[17];
    const float* wk       = (const float*)d_in[18];
    const float* bk       = (const float*)d_in[19];
    const float* wvp      = (const float*)d_in[20];
    const float* bvp      = (const float*)d_in[21];
    const float* wo       = (const float*)d_in[22];
    const float* bo       = (const float*)d_in[23];
    const float* sgq      = (const float*)d_in[24];

    const int N = in_sizes[0];
    const int E = in_sizes[3];
    const int S = in_sizes[4] / N;           // 256
    const int NBM1 = in_sizes[7] / HID - 1;  // bond-id clamp limit

    char* p = (char*)d_ws;
    auto alloc = [&](size_t b) -> char* {
        char* r = p; p += (b + 255) & ~(size_t)255; return r;
    };
    float* hbuf   = (float*)alloc((size_t)N * HID * 4);
    float* abuf   = (float*)alloc((size_t)N * HID * 4);  // agg -> t1 -> K
    float* zbuf   = (float*)alloc((size_t)N * HID * 4);  // z -> V
    float* tsc    = (float*)alloc((size_t)N * 4 * 4);
    int* deg      = (int*)alloc((size_t)N * 4);
    int* rowptr   = (int*)alloc((size_t)(N + 1) * 4);
    int* fill     = (int*)alloc((size_t)N * 4);
    int* csrc     = (int*)alloc((size_t)(E + N) * 4);
    int* ceid     = (int*)alloc((size_t)(E + N) * 4);
    int* bsum     = (int*)alloc(1024);
    int* boff     = (int*)alloc(1024);
    float* partial= (float*)alloc((size_t)NCB * HID * 4);
    double* stats = (double*)alloc(256);
    float* qvec   = (float*)alloc(512);
    float* mlbuf  = (float*)alloc((size_t)S * 8 * 4);
    int* cnt      = (int*)alloc((size_t)S * CNTSTRIDE * 4);
    int* flag     = (int*)alloc(256);
    int* list     = (int*)alloc((size_t)S * CAP * 4);
    float* tcomp  = (float*)alloc((size_t)S * CAP * 4 * 4);
    float* sub    = (float*)alloc((size_t)S * HID * 4);
    float* subo   = (float*)alloc((size_t)S * HID * 4);
    float* sgsc   = (float*)alloc((size_t)S * 4);

    const int mblocks = (N + 63) / 64;
    const int nb = (N + 255) / 256;   // 196 <= 256

    // mask layout detection (independent of everything else)
    hipMemsetAsync(flag, 0, 4, stream);
    detect_mask<<<1, 256, 0, stream>>>(mask, 2048, flag);

    // CSR build (once; topology is h-independent) — hierarchical scan
    init_deg<<<nb, 256, 0, stream>>>(deg, N);
    hist_kernel<<<(E + 255) / 256, 256, 0, stream>>>(ei, deg, E);
    block_reduce<<<nb, 256, 0, stream>>>(deg, bsum, N);
    scan_bsums<<<1, 256, 0, stream>>>(bsum, boff, nb);
    block_scan_write<<<nb, 256, 0, stream>>>(deg, boff, rowptr, N, E);
    hipMemsetAsync(fill, 0, (size_t)N * 4, stream);
    scatter_kernel<<<(E + N + 255) / 256, 256, 0, stream>>>(
        ei, eattr, rowptr, fill, csrc, ceid, E, N, NBM1);

    // node features: x = nan_to_num(concat(emb_atom[a], emb_fp[f]) @ w_proj + b)
    gemm128<2, false, false, true><<<mblocks, 256, 0, stream>>>(
        nullptr, nullptr, atom_ids, fp_ids, emb_atom, emb_fp,
        w_proj, b_proj, nullptr, hbuf, N, 2 * HID);

    for (int l = 0; l < 3; ++l) {
        gine_gather<<<(N * 64 + 255) / 256, 256, 0, stream>>>(
            rowptr, csrc, ceid, hbuf, emb_bond, abuf, N);
        // t1 = relu((h+agg) @ w1 + b1)   (t1 overwrites agg; row-private, safe)
        gemm128<1, true, false, false><<<mblocks, 256, 0, stream>>>(
            hbuf, abuf, nullptr, nullptr, nullptr, nullptr,
            mlp_w1 + (size_t)l * HID * HID, mlp_b1 + (size_t)l * HID,
            nullptr, abuf, N, HID);
        // z = t1 @ w2 + b2 + h
        gemm128<0, false, true, false><<<mblocks, 256, 0, stream>>>(
            abuf, nullptr, nullptr, nullptr, nullptr, nullptr,
            mlp_w2 + (size_t)l * HID * HID, mlp_b2 + (size_t)l * HID,
            hbuf, zbuf, N, HID);
        hipMemsetAsync(stats, 0, 16, stream);
        ln_stats<<<512, 256, 0, stream>>>(zbuf, stats, N * HID / 4);
        ln_silu<<<1024, 256, 0, stream>>>(zbuf, stats, ln_w + (size_t)l * HID,
                                          ln_b + (size_t)l * HID, hbuf,
                                          N * HID / 4, N * HID);
    }

    // attention pool
    colsum_part<<<NCB, 256, 0, stream>>>(hbuf, partial, N);
    qproj<<<1, 128, 0, stream>>>(partial, wq, bq, qvec, 1.0f / (float)N);
    float* Kbuf = abuf;   // t1 dead
    float* Vbuf = zbuf;   // z dead
    gemm128<0, false, false, false><<<mblocks, 256, 0, stream>>>(
        hbuf, nullptr, nullptr, nullptr, nullptr, nullptr, wk, bk, nullptr, Kbuf, N, HID);
    gemm128<0, false, false, false><<<mblocks, 256, 0, stream>>>(
        hbuf, nullptr, nullptr, nullptr, nullptr, nullptr, wvp, bvp, nullptr, Vbuf, N, HID);
    score_kernel<<<(N * 64 + 255) / 256, 256, 0, stream>>>(Kbuf, qvec, tsc, N);

    hipMemsetAsync(cnt, 0, (size_t)S * CNTSTRIDE * 4, stream);
    compact<<<dim3((N + 255) / 256, S), 256, 0, stream>>>(mask, flag, cnt, list, N);
    att_ml<<<S, 256, 0, stream>>>(tsc, cnt, list, mask, flag, mlbuf, tcomp, N);
    hipMemsetAsync(sub, 0, (size_t)S * HID * 4, stream);
    att_pv<<<dim3(NCHUNK, S), 256, 0, stream>>>(tsc, tcomp, Vbuf, cnt, list, mask,
                                                flag, mlbuf, sub, N);
    wo_kernel<<<S, 128, 0, stream>>>(sub, wo, bo, subo);
    sg_kernel<<<1, 256, 0, stream>>>(subo, sgq, sgsc, S);
    topk_kernel<<<1, 128, 0, stream>>>(sgsc, subo, (float*)d_out);
}